// Round 2
// 914.125 us; speedup vs baseline: 1.0385x; 1.0385x over previous
//
#include <hip/hip_runtime.h>
#include <math.h>

#define NN 16384
#define EE 262144
#define BB 8
#define TT 32
#define DD 256
#define HH 8
#define HDD 32

typedef __bf16 bf16;
typedef __bf16 bf16x8 __attribute__((ext_vector_type(8)));
typedef __bf16 bf16x4 __attribute__((ext_vector_type(4)));
typedef float f32x4 __attribute__((ext_vector_type(4)));

#define GM_F32 0
#define GM_BF16 1
#define GM_GELU 2
#define GM_RES 3
#define GM_RES2 4

__device__ __forceinline__ float gelu_f(float v) {
  return 0.5f * v * (1.f + erff(v * 0.70710678118654752440f));
}

// ---------------- LN for one 256-wide row (256 threads) ----------------
__device__ __forceinline__ void ln256(const float* __restrict__ xr,
                                      const float* __restrict__ g,
                                      const float* __restrict__ bb,
                                      bf16* __restrict__ o, float* red) {
  int t = threadIdx.x;
  float v = xr[t];
  float s = v, s2 = v * v;
#pragma unroll
  for (int off = 32; off > 0; off >>= 1) {
    s += __shfl_down(s, off, 64);
    s2 += __shfl_down(s2, off, 64);
  }
  int wv = t >> 6;
  if ((t & 63) == 0) { red[wv] = s; red[4 + wv] = s2; }
  __syncthreads();
  s = red[0] + red[1] + red[2] + red[3];
  s2 = red[4] + red[5] + red[6] + red[7];
  float m = s * (1.f / 256.f);
  float rs = rsqrtf(s2 * (1.f / 256.f) - m * m + 1e-5f);
  o[t] = (bf16)((v - m) * rs * g[t] + bb[t]);
}

// ---------------- fused prologue: cast9 | LN(x) | LN(v) | cnt | deg ----------------
struct Pro {
  const float* wsrc[9];
  bf16* wdst[9];
  int wblk[10];
  const float* x; const float* n1_g; const float* n1_b; bf16* xn;
  const float* v; const float* vn_g; const float* vn_b; bf16* vn;
  const int* batch; float* cntf;
  const int* ei; int* deg;
};

__global__ __launch_bounds__(256) void prologue(Pro p) {
  __shared__ float red[8];
  __shared__ int hist[BB];
  int b = blockIdx.x, t = threadIdx.x;
  if (b < 1280) {
    int s = 0;
    while (b >= p.wblk[s + 1]) ++s;
    int i = (b - p.wblk[s]) * 1024 + t * 4;
    const float4 f = *(const float4*)(p.wsrc[s] + i);
    bf16x4 o;
    o[0] = (bf16)f.x; o[1] = (bf16)f.y; o[2] = (bf16)f.z; o[3] = (bf16)f.w;
    *(bf16x4*)(p.wdst[s] + i) = o;
  } else if (b < 17664) {
    size_t r = b - 1280;
    ln256(p.x + r * 256, p.n1_g, p.n1_b, p.xn + r * 256, red);
  } else if (b < 17920) {
    size_t r = b - 17664;
    ln256(p.v + r * 256, p.vn_g, p.vn_b, p.vn + r * 256, red);
  } else if (b < 17984) {
    if (t < BB) hist[t] = 0;
    __syncthreads();
    int n = (b - 17920) * 256 + t;
    atomicAdd(&hist[p.batch[n]], 1);
    __syncthreads();
    if (t < BB) {
      int h = hist[t];
      if (h) atomicAdd(&p.cntf[t], (float)h);
    }
  } else {
    int e = (b - 17984) * 256 + t;
    atomicAdd(&p.deg[p.ei[EE + e]], 1);
  }
}

// ---------------- CSR build ----------------
__global__ __launch_bounds__(1024) void scan16k(const int* __restrict__ deg,
                                                int* __restrict__ offs, int* __restrict__ woff) {
  __shared__ int part[1024];
  int t = threadIdx.x;
  int base = t * 16;
  int v[16];
  int s = 0;
#pragma unroll
  for (int j = 0; j < 16; ++j) { v[j] = deg[base + j]; s += v[j]; }
  part[t] = s;
  __syncthreads();
  for (int o = 1; o < 1024; o <<= 1) {
    int x = (t >= o) ? part[t - o] : 0;
    __syncthreads();
    part[t] += x;
    __syncthreads();
  }
  int excl = part[t] - s;
#pragma unroll
  for (int j = 0; j < 16; ++j) {
    offs[base + j] = excl;
    woff[base + j] = excl;
    excl += v[j];
  }
  if (t == 1023) offs[NN] = part[1023];
}

// ---------------- MFMA GEMM core (32 rows x 64 cols per wave) ----------------
struct GemmP {
  const bf16* A; const bf16* W; const float* bias;
  int M, K, NC, mode;
  const float* res; const float* gamma;
  float* outf; bf16* outb;
};

__device__ __forceinline__ void gemm_core(const GemmP p, int bx, int by) {
  int wave = threadIdx.x >> 6;
  int lane = threadIdx.x & 63;
  int qd = lane >> 4;
  int l16 = lane & 15;
  int r0 = by * 128 + wave * 32;
  int c0 = bx * 64;
  int ar0 = r0 + l16;       if (ar0 >= p.M) ar0 = p.M - 1;
  int ar1 = r0 + 16 + l16;  if (ar1 >= p.M) ar1 = p.M - 1;
  const bf16* Ap0 = p.A + (size_t)ar0 * p.K + qd * 8;
  const bf16* Ap1 = p.A + (size_t)ar1 * p.K + qd * 8;
  const bf16* Wp = p.W + (size_t)(c0 + l16) * p.K + qd * 8;
  size_t K16 = (size_t)16 * p.K;
  f32x4 acc00 = {0.f, 0.f, 0.f, 0.f};
  f32x4 acc01 = acc00, acc02 = acc00, acc03 = acc00;
  f32x4 acc10 = acc00, acc11 = acc00, acc12 = acc00, acc13 = acc00;
  bf16x8 a0, a1, b0, b1, b2, b3, na0, na1, nb0, nb1, nb2, nb3;

#define GLOADS(A0, A1, B0, B1, B2, B3, kk)                \
  A0 = *(const bf16x8*)(Ap0 + (kk));                      \
  A1 = *(const bf16x8*)(Ap1 + (kk));                      \
  B0 = *(const bf16x8*)(Wp + (kk));                       \
  B1 = *(const bf16x8*)(Wp + K16 + (kk));                 \
  B2 = *(const bf16x8*)(Wp + 2 * K16 + (kk));             \
  B3 = *(const bf16x8*)(Wp + 3 * K16 + (kk));
#define GMFMAS(A0, A1, B0, B1, B2, B3)                                  \
  acc00 = __builtin_amdgcn_mfma_f32_16x16x32_bf16(A0, B0, acc00, 0, 0, 0); \
  acc01 = __builtin_amdgcn_mfma_f32_16x16x32_bf16(A0, B1, acc01, 0, 0, 0); \
  acc02 = __builtin_amdgcn_mfma_f32_16x16x32_bf16(A0, B2, acc02, 0, 0, 0); \
  acc03 = __builtin_amdgcn_mfma_f32_16x16x32_bf16(A0, B3, acc03, 0, 0, 0); \
  acc10 = __builtin_amdgcn_mfma_f32_16x16x32_bf16(A1, B0, acc10, 0, 0, 0); \
  acc11 = __builtin_amdgcn_mfma_f32_16x16x32_bf16(A1, B1, acc11, 0, 0, 0); \
  acc12 = __builtin_amdgcn_mfma_f32_16x16x32_bf16(A1, B2, acc12, 0, 0, 0); \
  acc13 = __builtin_amdgcn_mfma_f32_16x16x32_bf16(A1, B3, acc13, 0, 0, 0);

  GLOADS(a0, a1, b0, b1, b2, b3, 0)
  int k = 32;
  for (; k + 32 < p.K; k += 64) {
    GLOADS(na0, na1, nb0, nb1, nb2, nb3, k)
    GMFMAS(a0, a1, b0, b1, b2, b3)
    GLOADS(a0, a1, b0, b1, b2, b3, k + 32)
    GMFMAS(na0, na1, nb0, nb1, nb2, nb3)
  }
  GLOADS(na0, na1, nb0, nb1, nb2, nb3, k)
  GMFMAS(a0, a1, b0, b1, b2, b3)
  GMFMAS(na0, na1, nb0, nb1, nb2, nb3)
#undef GLOADS
#undef GMFMAS

  f32x4 accs[2][4] = {{acc00, acc01, acc02, acc03}, {acc10, acc11, acc12, acc13}};
#pragma unroll
  for (int s = 0; s < 2; ++s) {
#pragma unroll
    for (int c = 0; c < 4; ++c) {
      int col = c0 + c * 16 + l16;
      float bv = p.bias[col];
#pragma unroll
      for (int i = 0; i < 4; ++i) {
        int row = r0 + s * 16 + qd * 4 + i;
        if (row >= p.M) continue;
        size_t idx = (size_t)row * p.NC + col;
        float v = accs[s][c][i] + bv;
        if (p.mode == GM_F32) p.outf[idx] = v;
        else if (p.mode == GM_BF16) p.outb[idx] = (bf16)v;
        else if (p.mode == GM_GELU) p.outb[idx] = (bf16)gelu_f(v);
        else {
          float g = p.gamma ? p.gamma[col] : 1.f;
          float r = p.res[idx] + g * v;
          p.outf[idx] = r;
          if (p.mode == GM_RES2) p.outb[idx] = (bf16)r;
        }
      }
    }
  }
}

__global__ __launch_bounds__(256) void gemm_one(GemmP p, int nbx) {
  gemm_core(p, blockIdx.x % nbx, blockIdx.x / nbx);
}

// csr_fill + qh gemm merged (blocks [0,1024) fill, [1024,1032) qh)
__global__ __launch_bounds__(256) void csr_fill_qh(const int* __restrict__ ei,
                                                   int* __restrict__ woff,
                                                   int2* __restrict__ csr2, GemmP qp) {
  int b = blockIdx.x;
  if (b < 1024) {
    int e = b * 256 + threadIdx.x;
    int d = ei[EE + e];
    int s = ei[e];
    int p = atomicAdd(&woff[d], 1);
    csr2[p] = make_int2(e, s);
  } else {
    int l = b - 1024;
    gemm_core(qp, l % 4, l / 4);
  }
}

// GINE aggregation: block per node, wave per edge (4 in flight), lane covers 4 channels.
__global__ __launch_bounds__(256) void gine_agg(const float* __restrict__ eattr,
                                                const bf16* __restrict__ xn,
                                                const int* __restrict__ offs,
                                                const int2* __restrict__ csr2,
                                                const float* __restrict__ epsp,
                                                bf16* __restrict__ hin) {
  __shared__ f32x4 red[4][64];
  int n = blockIdx.x;
  int wave = threadIdx.x >> 6, lane = threadIdx.x & 63;
  int s0 = offs[n], s1 = offs[n + 1];
  f32x4 acc = {0.f, 0.f, 0.f, 0.f};
  int i = s0 + wave;
  int2 es = (i < s1) ? csr2[i] : make_int2(0, 0);
  for (; i < s1; i += 4) {
    int2 cur = es;
    int inext = i + 4;
    if (inext < s1) es = csr2[inext];
    float4 ea = *(const float4*)(eattr + (size_t)cur.x * DD + lane * 4);
    bf16x4 xv = *(const bf16x4*)(xn + (size_t)cur.y * DD + lane * 4);
    acc[0] += fmaxf((float)xv[0] + ea.x, 0.f);
    acc[1] += fmaxf((float)xv[1] + ea.y, 0.f);
    acc[2] += fmaxf((float)xv[2] + ea.z, 0.f);
    acc[3] += fmaxf((float)xv[3] + ea.w, 0.f);
  }
  red[wave][lane] = acc;
  __syncthreads();
  if (wave == 0) {
    f32x4 a = red[0][lane];
    f32x4 a1 = red[1][lane], a2 = red[2][lane], a3 = red[3][lane];
    bf16x4 xs = *(const bf16x4*)(xn + (size_t)n * DD + lane * 4);
    float e1 = 1.f + epsp[0];
    bf16x4 o;
#pragma unroll
    for (int j = 0; j < 4; ++j)
      o[j] = (bf16)(e1 * (float)xs[j] + a[j] + a1[j] + a2[j] + a3[j]);
    *(bf16x4*)(hin + (size_t)n * DD + lane * 4) = o;
  }
}

// ---------------- g_w1 GEMM fused with LN(512) + gelu ----------------
// block: 32 rows x 512 cols; wave w: cols [w*128, w*128+128)
__global__ __launch_bounds__(256) void gemm_g1_ln(const bf16* __restrict__ A,
                                                  const bf16* __restrict__ W,
                                                  const float* __restrict__ bias,
                                                  const float* __restrict__ lng,
                                                  const float* __restrict__ lnb,
                                                  bf16* __restrict__ out) {
  __shared__ float ssum[4][32], ssum2[4][32], smm[32], smr[32];
  int w = threadIdx.x >> 6, lane = threadIdx.x & 63;
  int qd = lane >> 4, l16 = lane & 15;
  int r0 = blockIdx.x * 32;
  int c0 = w * 128;
  const bf16* Ap0 = A + (size_t)(r0 + l16) * 256 + qd * 8;
  const bf16* Ap1 = Ap0 + (size_t)16 * 256;
  const bf16* Wp = W + (size_t)(c0 + l16) * 256 + qd * 8;
  f32x4 z = {0.f, 0.f, 0.f, 0.f};
  f32x4 acc0[8], acc1[8];
#pragma unroll
  for (int cf = 0; cf < 8; ++cf) { acc0[cf] = z; acc1[cf] = z; }
  for (int k = 0; k < 256; k += 32) {
    bf16x8 a0 = *(const bf16x8*)(Ap0 + k);
    bf16x8 a1 = *(const bf16x8*)(Ap1 + k);
#pragma unroll
    for (int cf = 0; cf < 8; ++cf) {
      bf16x8 bv = *(const bf16x8*)(Wp + (size_t)cf * 16 * 256 + k);
      acc0[cf] = __builtin_amdgcn_mfma_f32_16x16x32_bf16(a0, bv, acc0[cf], 0, 0, 0);
      acc1[cf] = __builtin_amdgcn_mfma_f32_16x16x32_bf16(a1, bv, acc1[cf], 0, 0, 0);
    }
  }
  // add bias
#pragma unroll
  for (int cf = 0; cf < 8; ++cf) {
    float bv = bias[c0 + cf * 16 + l16];
#pragma unroll
    for (int i = 0; i < 4; ++i) { acc0[cf][i] += bv; acc1[cf][i] += bv; }
  }
  // per-row partial sums (this wave's 128 cols), reduce over l16
#pragma unroll
  for (int s = 0; s < 2; ++s) {
#pragma unroll
    for (int i = 0; i < 4; ++i) {
      float ps = 0.f, ps2 = 0.f;
#pragma unroll
      for (int cf = 0; cf < 8; ++cf) {
        float v = s ? acc1[cf][i] : acc0[cf][i];
        ps += v; ps2 += v * v;
      }
#pragma unroll
      for (int off = 8; off > 0; off >>= 1) {
        ps += __shfl_down(ps, off, 16);
        ps2 += __shfl_down(ps2, off, 16);
      }
      if (l16 == 0) { int rib = s * 16 + qd * 4 + i; ssum[w][rib] = ps; ssum2[w][rib] = ps2; }
    }
  }
  __syncthreads();
  if (threadIdx.x < 32) {
    int rib = threadIdx.x;
    float S = ssum[0][rib] + ssum[1][rib] + ssum[2][rib] + ssum[3][rib];
    float S2 = ssum2[0][rib] + ssum2[1][rib] + ssum2[2][rib] + ssum2[3][rib];
    float m = S * (1.f / 512.f);
    smm[rib] = m;
    smr[rib] = rsqrtf(S2 * (1.f / 512.f) - m * m + 1e-5f);
  }
  __syncthreads();
#pragma unroll
  for (int s = 0; s < 2; ++s) {
#pragma unroll
    for (int cf = 0; cf < 8; ++cf) {
      int col = c0 + cf * 16 + l16;
      float g = lng[col], b = lnb[col];
#pragma unroll
      for (int i = 0; i < 4; ++i) {
        int rib = s * 16 + qd * 4 + i;
        float v = ((s ? acc1[cf][i] : acc0[cf][i]) - smm[rib]) * smr[rib] * g + b;
        out[(size_t)(r0 + rib) * 512 + col] = (bf16)gelu_f(v);
      }
    }
  }
}

// ---------------- GEMM + residual + LN(256) (+ optional seg-sum) ----------------
// block: 32 rows x 256 cols; wave w: cols [w*64, w*64+64)
struct ResLnP {
  const bf16* A; const bf16* W; const float* bias;
  const float* res; const float* gamma;
  float* resout; const float* lng; const float* lnb; bf16* lnout;
  int K; int seg; const int* batch; float* summary;
};

__global__ __launch_bounds__(256) void gemm_res_ln(ResLnP p) {
  __shared__ float ssum[4][32], ssum2[4][32], smm[32], smr[32];
  int w = threadIdx.x >> 6, lane = threadIdx.x & 63;
  int qd = lane >> 4, l16 = lane & 15;
  int r0 = blockIdx.x * 32;
  int c0 = w * 64;
  const bf16* Ap0 = p.A + (size_t)(r0 + l16) * p.K + qd * 8;
  const bf16* Ap1 = Ap0 + (size_t)16 * p.K;
  const bf16* Wp = p.W + (size_t)(c0 + l16) * p.K + qd * 8;
  size_t K16 = (size_t)16 * p.K;
  f32x4 z = {0.f, 0.f, 0.f, 0.f};
  f32x4 acc0[4], acc1[4];
#pragma unroll
  for (int cf = 0; cf < 4; ++cf) { acc0[cf] = z; acc1[cf] = z; }
  for (int k = 0; k < p.K; k += 32) {
    bf16x8 a0 = *(const bf16x8*)(Ap0 + k);
    bf16x8 a1 = *(const bf16x8*)(Ap1 + k);
#pragma unroll
    for (int cf = 0; cf < 4; ++cf) {
      bf16x8 bv = *(const bf16x8*)(Wp + cf * K16 + k);
      acc0[cf] = __builtin_amdgcn_mfma_f32_16x16x32_bf16(a0, bv, acc0[cf], 0, 0, 0);
      acc1[cf] = __builtin_amdgcn_mfma_f32_16x16x32_bf16(a1, bv, acc1[cf], 0, 0, 0);
    }
  }
  // bias + gamma*val + residual -> resout (f32), keep r in regs
  float rr0[4][4], rr1[4][4];
#pragma unroll
  for (int cf = 0; cf < 4; ++cf) {
    int col = c0 + cf * 16 + l16;
    float bv = p.bias[col], gm = p.gamma[col];
#pragma unroll
    for (int i = 0; i < 4; ++i) {
      {
        int row = r0 + qd * 4 + i;
        size_t idx = (size_t)row * 256 + col;
        float r = p.res[idx] + gm * (acc0[cf][i] + bv);
        p.resout[idx] = r; rr0[cf][i] = r;
      }
      {
        int row = r0 + 16 + qd * 4 + i;
        size_t idx = (size_t)row * 256 + col;
        float r = p.res[idx] + gm * (acc1[cf][i] + bv);
        p.resout[idx] = r; rr1[cf][i] = r;
      }
    }
  }
  // LN over 256 cols (cross-wave). NOTE: the first __syncthreads below also
  // guarantees all waves finished reading A before lnout (which may alias A
  // for the o-gemm: each block reads/writes exactly its own 32 rows).
#pragma unroll
  for (int s = 0; s < 2; ++s) {
#pragma unroll
    for (int i = 0; i < 4; ++i) {
      float ps = 0.f, ps2 = 0.f;
#pragma unroll
      for (int cf = 0; cf < 4; ++cf) {
        float v = s ? rr1[cf][i] : rr0[cf][i];
        ps += v; ps2 += v * v;
      }
#pragma unroll
      for (int off = 8; off > 0; off >>= 1) {
        ps += __shfl_down(ps, off, 16);
        ps2 += __shfl_down(ps2, off, 16);
      }
      if (l16 == 0) { int rib = s * 16 + qd * 4 + i; ssum[w][rib] = ps; ssum2[w][rib] = ps2; }
    }
  }
  __syncthreads();
  if (threadIdx.x < 32) {
    int rib = threadIdx.x;
    float S = ssum[0][rib] + ssum[1][rib] + ssum[2][rib] + ssum[3][rib];
    float S2 = ssum2[0][rib] + ssum2[1][rib] + ssum2[2][rib] + ssum2[3][rib];
    float m = S * (1.f / 256.f);
    smm[rib] = m;
    smr[rib] = rsqrtf(S2 * (1.f / 256.f) - m * m + 1e-5f);
  }
  __syncthreads();
#pragma unroll
  for (int cf = 0; cf < 4; ++cf) {
    int col = c0 + cf * 16 + l16;
    float lg = p.lng[col], lb = p.lnb[col];
#pragma unroll
    for (int i = 0; i < 4; ++i) {
      {
        int rib = qd * 4 + i;
        p.lnout[(size_t)(r0 + rib) * 256 + col] =
            (bf16)((rr0[cf][i] - smm[rib]) * smr[rib] * lg + lb);
      }
      {
        int rib = 16 + qd * 4 + i;
        p.lnout[(size_t)(r0 + rib) * 256 + col] =
            (bf16)((rr1[cf][i] - smm[rib]) * smr[rib] * lg + lb);
      }
    }
  }
  // fused segment-sum of resout rows into summary[batch][col]
  if (p.seg) {
    int b0 = p.batch[r0], b31 = p.batch[r0 + 31];
    if (b0 == b31) {
#pragma unroll
      for (int cf = 0; cf < 4; ++cf) {
        float sl = 0.f;
#pragma unroll
        for (int i = 0; i < 4; ++i) sl += rr0[cf][i] + rr1[cf][i];
        sl += __shfl_xor(sl, 16, 64);
        sl += __shfl_xor(sl, 32, 64);
        if (qd == 0) atomicAdd(&p.summary[(size_t)b0 * 256 + c0 + cf * 16 + l16], sl);
      }
    } else {
#pragma unroll
      for (int cf = 0; cf < 4; ++cf) {
        int col = c0 + cf * 16 + l16;
#pragma unroll
        for (int i = 0; i < 4; ++i) {
          atomicAdd(&p.summary[(size_t)p.batch[r0 + qd * 4 + i] * 256 + col], rr0[cf][i]);
          atomicAdd(&p.summary[(size_t)p.batch[r0 + 16 + qd * 4 + i] * 256 + col], rr1[cf][i]);
        }
      }
    }
  }
}

// ---------------- mid2: build_ctx [0,264) + q-gemm [264,776) ----------------
__global__ __launch_bounds__(256) void mid2(const float* __restrict__ summary,
                                            const float* __restrict__ cntf,
                                            const bf16* __restrict__ vn,
                                            bf16* __restrict__ ctx,
                                            GemmP qp) {
  int b = blockIdx.x, t = threadIdx.x;
  if (b < BB * (TT + 1)) {
    int bb = b / (TT + 1), k = b % (TT + 1);
    float val;
    if (k < TT) val = (float)vn[((size_t)(bb * TT + k)) * DD + t];
    else val = summary[(size_t)bb * DD + t] / fmaxf(cntf[bb], 1.f);
    ctx[(size_t)b * DD + t] = (bf16)val;
  } else {
    int l = b - BB * (TT + 1);
    gemm_core(qp, l % 4, l / 4);
  }
}

// ---------------- small MHA on v (B=8 blocks) ----------------
__global__ __launch_bounds__(256) void mha_small(const float* __restrict__ qh,
                                                 const float* __restrict__ kvh,
                                                 bf16* __restrict__ vatt) {
  int b = blockIdx.x;
  int h = threadIdx.x >> 5, qi = threadIdx.x & 31;
  const float scale = 0.17677669529663687f;
  float sc[TT + 1];
  float mx = -1e30f;
  const float* qp = qh + ((size_t)(b * TT + qi)) * DD + h * HDD;
#pragma unroll
  for (int k = 0; k < TT + 1; ++k) {
    const float* kp = kvh + ((size_t)(b * (TT + 1) + k)) * 512 + h * HDD;
    float s = 0.f;
#pragma unroll
    for (int d = 0; d < HDD; ++d) s += qp[d] * kp[d];
    s *= scale;
    sc[k] = s;
    mx = fmaxf(mx, s);
  }
  float sum = 0.f;
#pragma unroll
  for (int k = 0; k < TT + 1; ++k) {
    sc[k] = __expf(sc[k] - mx);
    sum += sc[k];
  }
  float inv = 1.f / sum;
#pragma unroll
  for (int d = 0; d < HDD; ++d) {
    float o = 0.f;
#pragma unroll
    for (int k = 0; k < TT + 1; ++k)
      o += sc[k] * kvh[((size_t)(b * (TT + 1) + k)) * 512 + 256 + h * HDD + d];
    vatt[((size_t)(b * TT + qi)) * DD + h * HDD + d] = (bf16)(o * inv);
  }
}

// ---------------- per-node cross attention (16 nodes per block) ----------------
__global__ __launch_bounds__(256) void cross_attn(const bf16* __restrict__ qx,
                                                  const float* __restrict__ kvx,
                                                  const int* __restrict__ batch,
                                                  bf16* __restrict__ attnout) {
  __shared__ float v_lds[TT * DD];  // 32 KB
  int tid = threadIdx.x;
  int n0 = blockIdx.x * 16;
  int b0 = batch[n0];
  for (int i = tid; i < TT * DD; i += 256) {
    int t = i >> 8, c = i & 255;
    v_lds[i] = kvx[((size_t)(b0 * TT + t)) * 512 + 256 + c];
  }
  int h = tid >> 5, lt = tid & 31;
  float kreg[HDD];
  {
    const float* kp = kvx + ((size_t)(b0 * TT + lt)) * 512 + h * HDD;
#pragma unroll
    for (int d = 0; d < HDD; ++d) kreg[d] = kp[d];
  }
  __syncthreads();
  const float scale = 0.17677669529663687f;
  for (int ni = 0; ni < 16; ++ni) {
    int n = n0 + ni;
    int b = batch[n];
    const bf16* qp = qx + (size_t)n * DD + h * HDD;
    float s = 0.f;
    if (b == b0) {
#pragma unroll
      for (int d = 0; d < HDD; ++d) s += (float)qp[d] * kreg[d];
    } else {
      const float* kp = kvx + ((size_t)(b * TT + lt)) * 512 + h * HDD;
#pragma unroll
      for (int d = 0; d < HDD; ++d) s += (float)qp[d] * kp[d];
    }
    s *= scale;
    float mx = s;
#pragma unroll
    for (int o = 16; o > 0; o >>= 1) mx = fmaxf(mx, __shfl_xor(mx, o, 32));
    float e = __expf(s - mx);
    float sum = e;
#pragma unroll
    for (int o = 16; o > 0; o >>= 1) sum += __shfl_xor(sum, o, 32);
    float a = e / sum;
    float o_acc = 0.f;
    int base_lane = (h & 1) << 5;
    if (b == b0) {
#pragma unroll
      for (int t = 0; t < TT; ++t) {
        float at = __shfl(a, base_lane + t, 64);
        o_acc += at * v_lds[t * DD + h * HDD + lt];
      }
    } else {
#pragma unroll
      for (int t = 0; t < TT; ++t) {
        float at = __shfl(a, base_lane + t, 64);
        o_acc += at * kvx[((size_t)(b * TT + t)) * 512 + 256 + h * HDD + lt];
      }
    }
    attnout[(size_t)n * DD + h * HDD + lt] = (bf16)o_acc;
  }
}

// ---------------- host launch ----------------
extern "C" void kernel_launch(void* const* d_in, const int* in_sizes, int n_in,
                              void* d_out, int out_size, void* d_ws, size_t ws_size,
                              hipStream_t stream) {
  const float* x = (const float*)d_in[0];
  const int* ei = (const int*)d_in[1];
  const float* eattr = (const float*)d_in[2];
  const float* v = (const float*)d_in[3];
  const int* batch = (const int*)d_in[4];
  const float* n1_g = (const float*)d_in[5];
  const float* n1_b = (const float*)d_in[6];
  const float* vn_g = (const float*)d_in[7];
  const float* vn_b = (const float*)d_in[8];
  const float* n3_g = (const float*)d_in[9];
  const float* n3_b = (const float*)d_in[10];
  const float* n4_g = (const float*)d_in[11];
  const float* n4_b = (const float*)d_in[12];
  const float* gine_eps = (const float*)d_in[13];
  const float* g_w1 = (const float*)d_in[14];
  const float* g_b1 = (const float*)d_in[15];
  const float* g_lng = (const float*)d_in[16];
  const float* g_lnb = (const float*)d_in[17];
  const float* g_w2 = (const float*)d_in[18];
  const float* g_b2 = (const float*)d_in[19];
  const float* gamma1 = (const float*)d_in[20];
  const float* gamma2 = (const float*)d_in[21];
  const float* gamma3 = (const float*)d_in[22];
  const float* mha_in_w = (const float*)d_in[23];
  const float* mha_in_b = (const float*)d_in[24];
  const float* mha_out_w = (const float*)d_in[25];
  const float* mha_out_b = (const float*)d_in[26];
  const float* q_w = (const float*)d_in[27];
  const float* q_b = (const float*)d_in[28];
  const float* kv_w = (const float*)d_in[29];
  const float* kv_b = (const float*)d_in[30];
  const float* o_w = (const float*)d_in[31];
  const float* o_b = (const float*)d_in[32];
  const float* f_w1 = (const float*)d_in[33];
  const float* f_b1 = (const float*)d_in[34];
  const float* f_w2 = (const float*)d_in[35];
  const float* f_b2 = (const float*)d_in[36];

  float* out_x = (float*)d_out;
  float* out_v = (float*)d_out + (size_t)NN * DD;

  char* wsp = (char*)d_ws;
  size_t off = 0;
  auto alloc = [&](size_t bytes) -> void* {
    void* p = wsp + off;
    off += (bytes + 255) & ~(size_t)255;
    return p;
  };
  // aliased arenas (lifetimes disjoint)
  float* t1f = (float*)alloc(33554432);  // S1: (unused f32) -> u bf16 (N x 1024)
  bf16* u_bf = (bf16*)t1f;
  bf16* xn_bf = (bf16*)alloc(8388608);   // S2: xn -> later qx
  bf16* qx_bf = xn_bf;
  bf16* t1g_bf = (bf16*)alloc(16777216); // S3: t1g bf16 -> later x2 f32
  float* x2f = (float*)t1g_bf;
  float* x1f = (float*)alloc(16777216);  // S4
  bf16* hin_bf = (bf16*)alloc(8388608);  // S5: hin -> later xn3
  bf16* xn3_bf = hin_bf;
  bf16* att_bf = (bf16*)alloc(8388608);  // S6: attnout -> later xn4 (same rows per block)
  bf16* xn4_bf = att_bf;
  // contiguous zero region: deg | summary | cntf
  int* deg = (int*)alloc(NN * 4);
  float* summary = (float*)alloc(BB * DD * 4);
  float* cntf = (float*)alloc(BB * 4);
  int* offs = (int*)alloc((NN + 1) * 4);
  int* woff = (int*)alloc(NN * 4);
  int2* csr2 = (int2*)alloc((size_t)EE * 8);
  bf16* vn_bf = (bf16*)alloc(BB * TT * DD * 2);
  bf16* ctx_bf = (bf16*)alloc(BB * (TT + 1) * DD * 2);
  float* qhf = (float*)alloc(BB * TT * DD * 4);
  float* kvhf = (float*)alloc(BB * (TT + 1) * 512 * 4);
  bf16* vatt_bf = (bf16*)alloc(BB * TT * DD * 2);
  bf16* vout_bf = (bf16*)alloc(BB * TT * DD * 2);
  float* kvxf = (float*)alloc(BB * TT * 512 * 4);
  bf16* wbuf = (bf16*)alloc((size_t)1310720 * 2);

  bf16* g_w1b = wbuf;
  bf16* g_w2b = g_w1b + 131072;
  bf16* mha_in_wb = g_w2b + 131072;
  bf16* q_wb = mha_in_wb + 196608;
  bf16* kv_wb = q_wb + 65536;
  bf16* o_wb = kv_wb + 131072;
  bf16* f_w1b = o_wb + 65536;
  bf16* f_w2b = f_w1b + 262144;
  bf16* mha_out_wb = f_w2b + 262144;

  // 0. zero deg+summary+cntf (contiguous; alloc pads each to 256B)
  hipMemsetAsync(deg, 0, NN * 4 + BB * DD * 4 + 256, stream);

  // 1. fused prologue
  Pro pr;
  pr.wsrc[0] = g_w1; pr.wdst[0] = g_w1b;
  pr.wsrc[1] = g_w2; pr.wdst[1] = g_w2b;
  pr.wsrc[2] = mha_in_w; pr.wdst[2] = mha_in_wb;
  pr.wsrc[3] = mha_out_w; pr.wdst[3] = mha_out_wb;
  pr.wsrc[4] = q_w; pr.wdst[4] = q_wb;
  pr.wsrc[5] = kv_w; pr.wdst[5] = kv_wb;
  pr.wsrc[6] = o_w; pr.wdst[6] = o_wb;
  pr.wsrc[7] = f_w1; pr.wdst[7] = f_w1b;
  pr.wsrc[8] = f_w2; pr.wdst[8] = f_w2b;
  int bs[10] = {0, 128, 256, 448, 512, 576, 704, 768, 1024, 1280};
  for (int i = 0; i < 10; ++i) pr.wblk[i] = bs[i];
  pr.x = x; pr.n1_g = n1_g; pr.n1_b = n1_b; pr.xn = xn_bf;
  pr.v = v; pr.vn_g = vn_g; pr.vn_b = vn_b; pr.vn = vn_bf;
  pr.batch = batch; pr.cntf = cntf;
  pr.ei = ei; pr.deg = deg;
  prologue<<<19008, 256, 0, stream>>>(pr);

  // 2. CSR scan
  scan16k<<<1, 1024, 0, stream>>>(deg, offs, woff);

  // 3. CSR fill + qh gemm (qh: vn @ wq.T, M=256, nbx=4, 8 blocks)
  GemmP j_qh = {vn_bf, mha_in_wb, mha_in_b, BB * TT, 256, 256, GM_F32,
                nullptr, nullptr, qhf, nullptr};
  csr_fill_qh<<<1024 + 8, 256, 0, stream>>>(ei, woff, csr2, j_qh);

  // 4. GINE aggregation
  gine_agg<<<NN, 256, 0, stream>>>(eattr, xn_bf, offs, csr2, gine_eps, hin_bf);

  // 5. g_w1 gemm fused with LN512+gelu -> t1g
  gemm_g1_ln<<<NN / 32, 256, 0, stream>>>(hin_bf, g_w1b, g_b1, g_lng, g_lnb, t1g_bf);

  // 6. g_w2 gemm + residual(x,gamma1) -> x1f, fused LN3 -> xn3, fused seg-sum -> summary
  ResLnP j_g2 = {t1g_bf, g_w2b, g_b2, x, gamma1, x1f, n3_g, n3_b, xn3_bf,
                 512, 1, batch, summary};
  gemm_res_ln<<<NN / 32, 256, 0, stream>>>(j_g2);

  // 7. build ctx + q gemm (xn3 -> qx)
  GemmP j_q = {xn3_bf, q_wb, q_b, NN, 256, 256, GM_BF16, nullptr, nullptr, nullptr, qx_bf};
  mid2<<<BB * (TT + 1) + 512, 256, 0, stream>>>(summary, cntf, vn_bf, ctx_bf, j_q);

  // 8. kvh gemm (M=264 -> nby=3)
  GemmP j_kvh = {ctx_bf, mha_in_wb + (size_t)256 * 256, mha_in_b + 256, BB * (TT + 1), 256, 512,
                 GM_F32, nullptr, nullptr, kvhf, nullptr};
  gemm_one<<<24, 256, 0, stream>>>(j_kvh, 8);

  // 9. small MHA
  mha_small<<<BB, 256, 0, stream>>>(qhf, kvhf, vatt_bf);

  // 10. mha out gemm -> out_v + vout_bf
  GemmP j_mo = {vatt_bf, mha_out_wb, mha_out_b, BB * TT, 256, 256, GM_RES2, v, gamma2, out_v, vout_bf};
  gemm_one<<<8, 256, 0, stream>>>(j_mo, 4);

  // 11. kv gemm -> kvx
  GemmP j_kv = {vout_bf, kv_wb, kv_b, BB * TT, 256, 512, GM_F32, nullptr, nullptr, kvxf, nullptr};
  gemm_one<<<16, 256, 0, stream>>>(j_kv, 8);

  // 12. cross attention
  cross_attn<<<NN / 16, 256, 0, stream>>>(qx_bf, kvxf, batch, att_bf);

  // 13. o gemm + residual(x1f,gamma3) -> x2f, fused LN4 -> xn4
  ResLnP j_o = {att_bf, o_wb, o_b, x1f, gamma3, x2f, n4_g, n4_b, xn4_bf,
                256, 0, nullptr, nullptr};
  gemm_res_ln<<<NN / 32, 256, 0, stream>>>(j_o);

  // 14. f_w1 gemm (gelu)
  GemmP j_f1 = {xn4_bf, f_w1b, f_b1, NN, 256, 1024, GM_GELU, nullptr, nullptr, nullptr, u_bf};
  gemm_one<<<2048, 256, 0, stream>>>(j_f1, 16);

  // 15. f_w2 gemm -> out_x
  GemmP j_f2 = {u_bf, f_w2b, f_b2, NN, 1024, 256, GM_RES, x2f, nullptr, out_x, nullptr};
  gemm_one<<<512, 256, 0, stream>>>(j_f2, 4);
}

// Round 3
// 888.714 us; speedup vs baseline: 1.0682x; 1.0286x over previous
//
#include <hip/hip_runtime.h>
#include <math.h>

#define NN 16384
#define EE 262144
#define BB 8
#define TT 32
#define DD 256
#define HH 8
#define HDD 32

typedef __bf16 bf16;
typedef __bf16 bf16x8 __attribute__((ext_vector_type(8)));
typedef __bf16 bf16x4 __attribute__((ext_vector_type(4)));
typedef float f32x4 __attribute__((ext_vector_type(4)));

#define GM_F32 0
#define GM_BF16 1
#define GM_GELU 2
#define GM_RES 3
#define GM_RES2 4

__device__ __forceinline__ float gelu_f(float v) {
  return 0.5f * v * (1.f + erff(v * 0.70710678118654752440f));
}

// ---------------- LN for one 256-wide row: ONE WAVE per row, no LDS/barrier ----------------
__device__ __forceinline__ void ln256w(const float* __restrict__ xr,
                                       const float* __restrict__ g,
                                       const float* __restrict__ bb,
                                       bf16* __restrict__ o) {
  int lane = threadIdx.x & 63;
  float4 v = *(const float4*)(xr + lane * 4);
  float s = v.x + v.y + v.z + v.w;
  float s2 = v.x * v.x + v.y * v.y + v.z * v.z + v.w * v.w;
#pragma unroll
  for (int off = 32; off > 0; off >>= 1) {
    s += __shfl_xor(s, off, 64);
    s2 += __shfl_xor(s2, off, 64);
  }
  float m = s * (1.f / 256.f);
  float rs = rsqrtf(s2 * (1.f / 256.f) - m * m + 1e-5f);
  float4 gg = *(const float4*)(g + lane * 4);
  float4 bv = *(const float4*)(bb + lane * 4);
  bf16x4 ov;
  ov[0] = (bf16)((v.x - m) * rs * gg.x + bv.x);
  ov[1] = (bf16)((v.y - m) * rs * gg.y + bv.y);
  ov[2] = (bf16)((v.z - m) * rs * gg.z + bv.z);
  ov[3] = (bf16)((v.w - m) * rs * gg.w + bv.w);
  *(bf16x4*)(o + lane * 4) = ov;
}

// ---------------- fused prologue: cast9 | LN(x) | LN(v) | cnt | deg ----------------
// block ranges: [0,1280) cast, [1280,5376) LN x (4 rows/blk), [5376,5440) LN v,
//               [5440,5504) cnt, [5504,6528) deg_count
struct Pro {
  const float* wsrc[9];
  bf16* wdst[9];
  int wblk[10];
  const float* x; const float* n1_g; const float* n1_b; bf16* xn;
  const float* v; const float* vn_g; const float* vn_b; bf16* vn;
  const int* batch; float* cntf;
  const int* ei; int* deg;
};

__global__ __launch_bounds__(256) void prologue(Pro p) {
  __shared__ int hist[BB];
  int b = blockIdx.x, t = threadIdx.x;
  int wave = t >> 6;
  if (b < 1280) {
    int s = 0;
    while (b >= p.wblk[s + 1]) ++s;
    int i = (b - p.wblk[s]) * 1024 + t * 4;
    const float4 f = *(const float4*)(p.wsrc[s] + i);
    bf16x4 o;
    o[0] = (bf16)f.x; o[1] = (bf16)f.y; o[2] = (bf16)f.z; o[3] = (bf16)f.w;
    *(bf16x4*)(p.wdst[s] + i) = o;
  } else if (b < 5376) {
    size_t r = (size_t)(b - 1280) * 4 + wave;
    ln256w(p.x + r * 256, p.n1_g, p.n1_b, p.xn + r * 256);
  } else if (b < 5440) {
    size_t r = (size_t)(b - 5376) * 4 + wave;
    ln256w(p.v + r * 256, p.vn_g, p.vn_b, p.vn + r * 256);
  } else if (b < 5504) {
    if (t < BB) hist[t] = 0;
    __syncthreads();
    int n = (b - 5440) * 256 + t;
    atomicAdd(&hist[p.batch[n]], 1);
    __syncthreads();
    if (t < BB) {
      int h = hist[t];
      if (h) atomicAdd(&p.cntf[t], (float)h);
    }
  } else {
    int e = (b - 5504) * 256 + t;
    atomicAdd(&p.deg[p.ei[EE + e]], 1);
  }
}

// ---------------- CSR build ----------------
__global__ __launch_bounds__(1024) void scan16k(const int* __restrict__ deg,
                                                int* __restrict__ offs, int* __restrict__ woff) {
  __shared__ int part[1024];
  int t = threadIdx.x;
  int base = t * 16;
  int v[16];
  int s = 0;
#pragma unroll
  for (int j = 0; j < 16; ++j) { v[j] = deg[base + j]; s += v[j]; }
  part[t] = s;
  __syncthreads();
  for (int o = 1; o < 1024; o <<= 1) {
    int x = (t >= o) ? part[t - o] : 0;
    __syncthreads();
    part[t] += x;
    __syncthreads();
  }
  int excl = part[t] - s;
#pragma unroll
  for (int j = 0; j < 16; ++j) {
    offs[base + j] = excl;
    woff[base + j] = excl;
    excl += v[j];
  }
  if (t == 1023) offs[NN] = part[1023];
}

// ---------------- MFMA GEMM core (32 rows x 64 cols per wave) ----------------
struct GemmP {
  const bf16* A; const bf16* W; const float* bias;
  int M, K, NC, mode;
  const float* res; const float* gamma;
  float* outf; bf16* outb;
};

__device__ __forceinline__ void gemm_core(const GemmP p, int bx, int by) {
  int wave = threadIdx.x >> 6;
  int lane = threadIdx.x & 63;
  int qd = lane >> 4;
  int l16 = lane & 15;
  int r0 = by * 128 + wave * 32;
  int c0 = bx * 64;
  int ar0 = r0 + l16;       if (ar0 >= p.M) ar0 = p.M - 1;
  int ar1 = r0 + 16 + l16;  if (ar1 >= p.M) ar1 = p.M - 1;
  const bf16* Ap0 = p.A + (size_t)ar0 * p.K + qd * 8;
  const bf16* Ap1 = p.A + (size_t)ar1 * p.K + qd * 8;
  const bf16* Wp = p.W + (size_t)(c0 + l16) * p.K + qd * 8;
  size_t K16 = (size_t)16 * p.K;
  f32x4 acc00 = {0.f, 0.f, 0.f, 0.f};
  f32x4 acc01 = acc00, acc02 = acc00, acc03 = acc00;
  f32x4 acc10 = acc00, acc11 = acc00, acc12 = acc00, acc13 = acc00;
  bf16x8 a0, a1, b0, b1, b2, b3, na0, na1, nb0, nb1, nb2, nb3;

#define GLOADS(A0, A1, B0, B1, B2, B3, kk)                \
  A0 = *(const bf16x8*)(Ap0 + (kk));                      \
  A1 = *(const bf16x8*)(Ap1 + (kk));                      \
  B0 = *(const bf16x8*)(Wp + (kk));                       \
  B1 = *(const bf16x8*)(Wp + K16 + (kk));                 \
  B2 = *(const bf16x8*)(Wp + 2 * K16 + (kk));             \
  B3 = *(const bf16x8*)(Wp + 3 * K16 + (kk));
#define GMFMAS(A0, A1, B0, B1, B2, B3)                                  \
  acc00 = __builtin_amdgcn_mfma_f32_16x16x32_bf16(A0, B0, acc00, 0, 0, 0); \
  acc01 = __builtin_amdgcn_mfma_f32_16x16x32_bf16(A0, B1, acc01, 0, 0, 0); \
  acc02 = __builtin_amdgcn_mfma_f32_16x16x32_bf16(A0, B2, acc02, 0, 0, 0); \
  acc03 = __builtin_amdgcn_mfma_f32_16x16x32_bf16(A0, B3, acc03, 0, 0, 0); \
  acc10 = __builtin_amdgcn_mfma_f32_16x16x32_bf16(A1, B0, acc10, 0, 0, 0); \
  acc11 = __builtin_amdgcn_mfma_f32_16x16x32_bf16(A1, B1, acc11, 0, 0, 0); \
  acc12 = __builtin_amdgcn_mfma_f32_16x16x32_bf16(A1, B2, acc12, 0, 0, 0); \
  acc13 = __builtin_amdgcn_mfma_f32_16x16x32_bf16(A1, B3, acc13, 0, 0, 0);

  GLOADS(a0, a1, b0, b1, b2, b3, 0)
  int k = 32;
  for (; k + 32 < p.K; k += 64) {
    GLOADS(na0, na1, nb0, nb1, nb2, nb3, k)
    GMFMAS(a0, a1, b0, b1, b2, b3)
    GLOADS(a0, a1, b0, b1, b2, b3, k + 32)
    GMFMAS(na0, na1, nb0, nb1, nb2, nb3)
  }
  GLOADS(na0, na1, nb0, nb1, nb2, nb3, k)
  GMFMAS(a0, a1, b0, b1, b2, b3)
  GMFMAS(na0, na1, nb0, nb1, nb2, nb3)
#undef GLOADS
#undef GMFMAS

  f32x4 accs[2][4] = {{acc00, acc01, acc02, acc03}, {acc10, acc11, acc12, acc13}};
#pragma unroll
  for (int s = 0; s < 2; ++s) {
#pragma unroll
    for (int c = 0; c < 4; ++c) {
      int col = c0 + c * 16 + l16;
      float bv = p.bias[col];
#pragma unroll
      for (int i = 0; i < 4; ++i) {
        int row = r0 + s * 16 + qd * 4 + i;
        if (row >= p.M) continue;
        size_t idx = (size_t)row * p.NC + col;
        float v = accs[s][c][i] + bv;
        if (p.mode == GM_F32) p.outf[idx] = v;
        else if (p.mode == GM_BF16) p.outb[idx] = (bf16)v;
        else if (p.mode == GM_GELU) p.outb[idx] = (bf16)gelu_f(v);
        else {
          float g = p.gamma ? p.gamma[col] : 1.f;
          float r = p.res[idx] + g * v;
          p.outf[idx] = r;
          if (p.mode == GM_RES2) p.outb[idx] = (bf16)r;
        }
      }
    }
  }
}

__global__ __launch_bounds__(256) void gemm_one(GemmP p, int nbx) {
  gemm_core(p, blockIdx.x % nbx, blockIdx.x / nbx);
}

// csr_fill + qh gemm merged (blocks [0,1024) fill, [1024,1032) qh)
__global__ __launch_bounds__(256) void csr_fill_qh(const int* __restrict__ ei,
                                                   int* __restrict__ woff,
                                                   int2* __restrict__ csr2, GemmP qp) {
  int b = blockIdx.x;
  if (b < 1024) {
    int e = b * 256 + threadIdx.x;
    int d = ei[EE + e];
    int s = ei[e];
    int p = atomicAdd(&woff[d], 1);
    csr2[p] = make_int2(e, s);
  } else {
    int l = b - 1024;
    gemm_core(qp, l % 4, l / 4);
  }
}

// GINE aggregation: ONE WAVE per node (4 nodes/block), lane covers 4 channels.
__global__ __launch_bounds__(256) void gine_agg(const float* __restrict__ eattr,
                                                const bf16* __restrict__ xn,
                                                const int* __restrict__ offs,
                                                const int2* __restrict__ csr2,
                                                const float* __restrict__ epsp,
                                                bf16* __restrict__ hin) {
  int wave = threadIdx.x >> 6, lane = threadIdx.x & 63;
  int n = blockIdx.x * 4 + wave;
  int s0 = offs[n], s1 = offs[n + 1];
  f32x4 acc = {0.f, 0.f, 0.f, 0.f};
  int i = s0;
  int2 es = (i < s1) ? csr2[i] : make_int2(0, 0);
  for (; i < s1; ++i) {
    int2 cur = es;
    if (i + 1 < s1) es = csr2[i + 1];
    float4 ea = *(const float4*)(eattr + (size_t)cur.x * DD + lane * 4);
    bf16x4 xv = *(const bf16x4*)(xn + (size_t)cur.y * DD + lane * 4);
    acc[0] += fmaxf((float)xv[0] + ea.x, 0.f);
    acc[1] += fmaxf((float)xv[1] + ea.y, 0.f);
    acc[2] += fmaxf((float)xv[2] + ea.z, 0.f);
    acc[3] += fmaxf((float)xv[3] + ea.w, 0.f);
  }
  bf16x4 xs = *(const bf16x4*)(xn + (size_t)n * DD + lane * 4);
  float e1 = 1.f + epsp[0];
  bf16x4 o;
#pragma unroll
  for (int j = 0; j < 4; ++j)
    o[j] = (bf16)(e1 * (float)xs[j] + acc[j]);
  *(bf16x4*)(hin + (size_t)n * DD + lane * 4) = o;
}

// ---------------- g_w1 GEMM fused with LN(512) + gelu ----------------
// block: 32 rows x 512 cols; wave w: cols [w*128, w*128+128)
__global__ __launch_bounds__(256) void gemm_g1_ln(const bf16* __restrict__ A,
                                                  const bf16* __restrict__ W,
                                                  const float* __restrict__ bias,
                                                  const float* __restrict__ lng,
                                                  const float* __restrict__ lnb,
                                                  bf16* __restrict__ out) {
  __shared__ float ssum[4][32], ssum2[4][32], smm[32], smr[32];
  int w = threadIdx.x >> 6, lane = threadIdx.x & 63;
  int qd = lane >> 4, l16 = lane & 15;
  int r0 = blockIdx.x * 32;
  int c0 = w * 128;
  const bf16* Ap0 = A + (size_t)(r0 + l16) * 256 + qd * 8;
  const bf16* Ap1 = Ap0 + (size_t)16 * 256;
  const bf16* Wp = W + (size_t)(c0 + l16) * 256 + qd * 8;
  f32x4 z = {0.f, 0.f, 0.f, 0.f};
  f32x4 acc0[8], acc1[8];
#pragma unroll
  for (int cf = 0; cf < 8; ++cf) { acc0[cf] = z; acc1[cf] = z; }
  for (int k = 0; k < 256; k += 32) {
    bf16x8 a0 = *(const bf16x8*)(Ap0 + k);
    bf16x8 a1 = *(const bf16x8*)(Ap1 + k);
#pragma unroll
    for (int cf = 0; cf < 8; ++cf) {
      bf16x8 bv = *(const bf16x8*)(Wp + (size_t)cf * 16 * 256 + k);
      acc0[cf] = __builtin_amdgcn_mfma_f32_16x16x32_bf16(a0, bv, acc0[cf], 0, 0, 0);
      acc1[cf] = __builtin_amdgcn_mfma_f32_16x16x32_bf16(a1, bv, acc1[cf], 0, 0, 0);
    }
  }
  // add bias
#pragma unroll
  for (int cf = 0; cf < 8; ++cf) {
    float bv = bias[c0 + cf * 16 + l16];
#pragma unroll
    for (int i = 0; i < 4; ++i) { acc0[cf][i] += bv; acc1[cf][i] += bv; }
  }
  // per-row partial sums (this wave's 128 cols), reduce over l16
#pragma unroll
  for (int s = 0; s < 2; ++s) {
#pragma unroll
    for (int i = 0; i < 4; ++i) {
      float ps = 0.f, ps2 = 0.f;
#pragma unroll
      for (int cf = 0; cf < 8; ++cf) {
        float v = s ? acc1[cf][i] : acc0[cf][i];
        ps += v; ps2 += v * v;
      }
#pragma unroll
      for (int off = 8; off > 0; off >>= 1) {
        ps += __shfl_down(ps, off, 16);
        ps2 += __shfl_down(ps2, off, 16);
      }
      if (l16 == 0) { int rib = s * 16 + qd * 4 + i; ssum[w][rib] = ps; ssum2[w][rib] = ps2; }
    }
  }
  __syncthreads();
  if (threadIdx.x < 32) {
    int rib = threadIdx.x;
    float S = ssum[0][rib] + ssum[1][rib] + ssum[2][rib] + ssum[3][rib];
    float S2 = ssum2[0][rib] + ssum2[1][rib] + ssum2[2][rib] + ssum2[3][rib];
    float m = S * (1.f / 512.f);
    smm[rib] = m;
    smr[rib] = rsqrtf(S2 * (1.f / 512.f) - m * m + 1e-5f);
  }
  __syncthreads();
#pragma unroll
  for (int s = 0; s < 2; ++s) {
#pragma unroll
    for (int cf = 0; cf < 8; ++cf) {
      int col = c0 + cf * 16 + l16;
      float g = lng[col], b = lnb[col];
#pragma unroll
      for (int i = 0; i < 4; ++i) {
        int rib = s * 16 + qd * 4 + i;
        float v = ((s ? acc1[cf][i] : acc0[cf][i]) - smm[rib]) * smr[rib] * g + b;
        out[(size_t)(r0 + rib) * 512 + col] = (bf16)gelu_f(v);
      }
    }
  }
}

// ---------------- GEMM + residual + LN(256) (+ optional seg-sum) ----------------
// block: 32 rows x 256 cols; wave w: cols [w*64, w*64+64)
struct ResLnP {
  const bf16* A; const bf16* W; const float* bias;
  const float* res; const float* gamma;
  float* resout; const float* lng; const float* lnb; bf16* lnout;
  int K; int seg; const int* batch; float* summary;
};

__global__ __launch_bounds__(256) void gemm_res_ln(ResLnP p) {
  __shared__ float ssum[4][32], ssum2[4][32], smm[32], smr[32];
  int w = threadIdx.x >> 6, lane = threadIdx.x & 63;
  int qd = lane >> 4, l16 = lane & 15;
  int r0 = blockIdx.x * 32;
  int c0 = w * 64;
  const bf16* Ap0 = p.A + (size_t)(r0 + l16) * p.K + qd * 8;
  const bf16* Ap1 = Ap0 + (size_t)16 * p.K;
  const bf16* Wp = p.W + (size_t)(c0 + l16) * p.K + qd * 8;
  size_t K16 = (size_t)16 * p.K;
  f32x4 z = {0.f, 0.f, 0.f, 0.f};
  f32x4 acc0[4], acc1[4];
#pragma unroll
  for (int cf = 0; cf < 4; ++cf) { acc0[cf] = z; acc1[cf] = z; }
  for (int k = 0; k < p.K; k += 32) {
    bf16x8 a0 = *(const bf16x8*)(Ap0 + k);
    bf16x8 a1 = *(const bf16x8*)(Ap1 + k);
#pragma unroll
    for (int cf = 0; cf < 4; ++cf) {
      bf16x8 bv = *(const bf16x8*)(Wp + cf * K16 + k);
      acc0[cf] = __builtin_amdgcn_mfma_f32_16x16x32_bf16(a0, bv, acc0[cf], 0, 0, 0);
      acc1[cf] = __builtin_amdgcn_mfma_f32_16x16x32_bf16(a1, bv, acc1[cf], 0, 0, 0);
    }
  }
  // bias + gamma*val + residual -> resout (f32), keep r in regs
  float rr0[4][4], rr1[4][4];
#pragma unroll
  for (int cf = 0; cf < 4; ++cf) {
    int col = c0 + cf * 16 + l16;
    float bv = p.bias[col], gm = p.gamma[col];
#pragma unroll
    for (int i = 0; i < 4; ++i) {
      {
        int row = r0 + qd * 4 + i;
        size_t idx = (size_t)row * 256 + col;
        float r = p.res[idx] + gm * (acc0[cf][i] + bv);
        p.resout[idx] = r; rr0[cf][i] = r;
      }
      {
        int row = r0 + 16 + qd * 4 + i;
        size_t idx = (size_t)row * 256 + col;
        float r = p.res[idx] + gm * (acc1[cf][i] + bv);
        p.resout[idx] = r; rr1[cf][i] = r;
      }
    }
  }
  // LN over 256 cols (cross-wave). NOTE: the first __syncthreads below also
  // guarantees all waves finished reading A before lnout (which may alias A
  // for the o-gemm: each block reads/writes exactly its own 32 rows).
#pragma unroll
  for (int s = 0; s < 2; ++s) {
#pragma unroll
    for (int i = 0; i < 4; ++i) {
      float ps = 0.f, ps2 = 0.f;
#pragma unroll
      for (int cf = 0; cf < 4; ++cf) {
        float v = s ? rr1[cf][i] : rr0[cf][i];
        ps += v; ps2 += v * v;
      }
#pragma unroll
      for (int off = 8; off > 0; off >>= 1) {
        ps += __shfl_down(ps, off, 16);
        ps2 += __shfl_down(ps2, off, 16);
      }
      if (l16 == 0) { int rib = s * 16 + qd * 4 + i; ssum[w][rib] = ps; ssum2[w][rib] = ps2; }
    }
  }
  __syncthreads();
  if (threadIdx.x < 32) {
    int rib = threadIdx.x;
    float S = ssum[0][rib] + ssum[1][rib] + ssum[2][rib] + ssum[3][rib];
    float S2 = ssum2[0][rib] + ssum2[1][rib] + ssum2[2][rib] + ssum2[3][rib];
    float m = S * (1.f / 256.f);
    smm[rib] = m;
    smr[rib] = rsqrtf(S2 * (1.f / 256.f) - m * m + 1e-5f);
  }
  __syncthreads();
#pragma unroll
  for (int cf = 0; cf < 4; ++cf) {
    int col = c0 + cf * 16 + l16;
    float lg = p.lng[col], lb = p.lnb[col];
#pragma unroll
    for (int i = 0; i < 4; ++i) {
      {
        int rib = qd * 4 + i;
        p.lnout[(size_t)(r0 + rib) * 256 + col] =
            (bf16)((rr0[cf][i] - smm[rib]) * smr[rib] * lg + lb);
      }
      {
        int rib = 16 + qd * 4 + i;
        p.lnout[(size_t)(r0 + rib) * 256 + col] =
            (bf16)((rr1[cf][i] - smm[rib]) * smr[rib] * lg + lb);
      }
    }
  }
  // fused segment-sum of resout rows into summary[batch][col]
  if (p.seg) {
    int b0 = p.batch[r0], b31 = p.batch[r0 + 31];
    if (b0 == b31) {
#pragma unroll
      for (int cf = 0; cf < 4; ++cf) {
        float sl = 0.f;
#pragma unroll
        for (int i = 0; i < 4; ++i) sl += rr0[cf][i] + rr1[cf][i];
        sl += __shfl_xor(sl, 16, 64);
        sl += __shfl_xor(sl, 32, 64);
        if (qd == 0) atomicAdd(&p.summary[(size_t)b0 * 256 + c0 + cf * 16 + l16], sl);
      }
    } else {
#pragma unroll
      for (int cf = 0; cf < 4; ++cf) {
        int col = c0 + cf * 16 + l16;
#pragma unroll
        for (int i = 0; i < 4; ++i) {
          atomicAdd(&p.summary[(size_t)p.batch[r0 + qd * 4 + i] * 256 + col], rr0[cf][i]);
          atomicAdd(&p.summary[(size_t)p.batch[r0 + 16 + qd * 4 + i] * 256 + col], rr1[cf][i]);
        }
      }
    }
  }
}

// ---------------- fused FFN: out = x2 + gelu(xn4 @ W1.T + b1) @ W2.T + b2 ----------------
// block: 32 rows; phase1 wave w -> cols [w*256,+256) of u (kept in LDS);
// phase2 wave w -> out cols [w*64,+64), K=1024 from LDS.
__global__ __launch_bounds__(256) void gemm_ffn(const bf16* __restrict__ A,
                                                const bf16* __restrict__ W1,
                                                const float* __restrict__ b1,
                                                const bf16* __restrict__ W2,
                                                const float* __restrict__ b2,
                                                const float* __restrict__ res,
                                                float* __restrict__ outx) {
  __shared__ bf16 t_lds[32 * 1032];  // row stride 1032 (pad 8): 2064B = 4 banks mod 32
  int w = threadIdx.x >> 6, lane = threadIdx.x & 63;
  int qd = lane >> 4, l16 = lane & 15;
  int r0 = blockIdx.x * 32;
  // ---- phase 1: u[32][c0..c0+256) = gelu(A @ W1.T + b1) -> LDS
  {
    int c0 = w * 256;
    const bf16* Ap0 = A + (size_t)(r0 + l16) * 256 + qd * 8;
    const bf16* Ap1 = Ap0 + (size_t)16 * 256;
    const bf16* Wp = W1 + (size_t)(c0 + l16) * 256 + qd * 8;
    f32x4 z = {0.f, 0.f, 0.f, 0.f};
    f32x4 acc0[16], acc1[16];
#pragma unroll
    for (int cf = 0; cf < 16; ++cf) { acc0[cf] = z; acc1[cf] = z; }
    for (int k = 0; k < 256; k += 32) {
      bf16x8 a0 = *(const bf16x8*)(Ap0 + k);
      bf16x8 a1 = *(const bf16x8*)(Ap1 + k);
#pragma unroll
      for (int cf = 0; cf < 16; ++cf) {
        bf16x8 bv = *(const bf16x8*)(Wp + (size_t)cf * 16 * 256 + k);
        acc0[cf] = __builtin_amdgcn_mfma_f32_16x16x32_bf16(a0, bv, acc0[cf], 0, 0, 0);
        acc1[cf] = __builtin_amdgcn_mfma_f32_16x16x32_bf16(a1, bv, acc1[cf], 0, 0, 0);
      }
    }
#pragma unroll
    for (int cf = 0; cf < 16; ++cf) {
      int col = c0 + cf * 16 + l16;
      float bv = b1[col];
#pragma unroll
      for (int i = 0; i < 4; ++i) {
        int rib0 = qd * 4 + i, rib1 = 16 + qd * 4 + i;
        t_lds[rib0 * 1032 + col] = (bf16)gelu_f(acc0[cf][i] + bv);
        t_lds[rib1 * 1032 + col] = (bf16)gelu_f(acc1[cf][i] + bv);
      }
    }
  }
  __syncthreads();
  // ---- phase 2: out[32][c2..c2+64) = u @ W2.T + b2 + res
  {
    int c2 = w * 64;
    const bf16* Wp2 = W2 + (size_t)(c2 + l16) * 1024 + qd * 8;
    const bf16* lp0 = t_lds + l16 * 1032 + qd * 8;
    const bf16* lp1 = t_lds + (16 + l16) * 1032 + qd * 8;
    f32x4 z = {0.f, 0.f, 0.f, 0.f};
    f32x4 acc0[4], acc1[4];
#pragma unroll
    for (int cf = 0; cf < 4; ++cf) { acc0[cf] = z; acc1[cf] = z; }
    for (int k = 0; k < 1024; k += 32) {
      bf16x8 a0 = *(const bf16x8*)(lp0 + k);
      bf16x8 a1 = *(const bf16x8*)(lp1 + k);
#pragma unroll
      for (int cf = 0; cf < 4; ++cf) {
        bf16x8 bv = *(const bf16x8*)(Wp2 + (size_t)cf * 16 * 1024 + k);
        acc0[cf] = __builtin_amdgcn_mfma_f32_16x16x32_bf16(a0, bv, acc0[cf], 0, 0, 0);
        acc1[cf] = __builtin_amdgcn_mfma_f32_16x16x32_bf16(a1, bv, acc1[cf], 0, 0, 0);
      }
    }
#pragma unroll
    for (int cf = 0; cf < 4; ++cf) {
      int col = c2 + cf * 16 + l16;
      float bv = b2[col];
#pragma unroll
      for (int i = 0; i < 4; ++i) {
        int row0 = r0 + qd * 4 + i, row1 = row0 + 16;
        size_t i0 = (size_t)row0 * 256 + col, i1 = (size_t)row1 * 256 + col;
        outx[i0] = res[i0] + acc0[cf][i] + bv;
        outx[i1] = res[i1] + acc1[cf][i] + bv;
      }
    }
  }
}

// ---------------- mid2: build_ctx [0,264) + q-gemm [264,776) ----------------
__global__ __launch_bounds__(256) void mid2(const float* __restrict__ summary,
                                            const float* __restrict__ cntf,
                                            const bf16* __restrict__ vn,
                                            bf16* __restrict__ ctx,
                                            GemmP qp) {
  int b = blockIdx.x, t = threadIdx.x;
  if (b < BB * (TT + 1)) {
    int bb = b / (TT + 1), k = b % (TT + 1);
    float val;
    if (k < TT) val = (float)vn[((size_t)(bb * TT + k)) * DD + t];
    else val = summary[(size_t)bb * DD + t] / fmaxf(cntf[bb], 1.f);
    ctx[(size_t)b * DD + t] = (bf16)val;
  } else {
    int l = b - BB * (TT + 1);
    gemm_core(qp, l % 4, l / 4);
  }
}

// ---------------- small MHA on v (B=8 blocks) ----------------
__global__ __launch_bounds__(256) void mha_small(const float* __restrict__ qh,
                                                 const float* __restrict__ kvh,
                                                 bf16* __restrict__ vatt) {
  int b = blockIdx.x;
  int h = threadIdx.x >> 5, qi = threadIdx.x & 31;
  const float scale = 0.17677669529663687f;
  float sc[TT + 1];
  float mx = -1e30f;
  const float* qp = qh + ((size_t)(b * TT + qi)) * DD + h * HDD;
#pragma unroll
  for (int k = 0; k < TT + 1; ++k) {
    const float* kp = kvh + ((size_t)(b * (TT + 1) + k)) * 512 + h * HDD;
    float s = 0.f;
#pragma unroll
    for (int d = 0; d < HDD; ++d) s += qp[d] * kp[d];
    s *= scale;
    sc[k] = s;
    mx = fmaxf(mx, s);
  }
  float sum = 0.f;
#pragma unroll
  for (int k = 0; k < TT + 1; ++k) {
    sc[k] = __expf(sc[k] - mx);
    sum += sc[k];
  }
  float inv = 1.f / sum;
#pragma unroll
  for (int d = 0; d < HDD; ++d) {
    float o = 0.f;
#pragma unroll
    for (int k = 0; k < TT + 1; ++k)
      o += sc[k] * kvh[((size_t)(b * (TT + 1) + k)) * 512 + 256 + h * HDD + d];
    vatt[((size_t)(b * TT + qi)) * DD + h * HDD + d] = (bf16)(o * inv);
  }
}

// ---------------- per-node cross attention (16 nodes per block) ----------------
__global__ __launch_bounds__(256) void cross_attn(const bf16* __restrict__ qx,
                                                  const float* __restrict__ kvx,
                                                  const int* __restrict__ batch,
                                                  bf16* __restrict__ attnout) {
  __shared__ float v_lds[TT * DD];  // 32 KB
  int tid = threadIdx.x;
  int n0 = blockIdx.x * 16;
  int b0 = batch[n0];
  for (int i = tid; i < TT * DD; i += 256) {
    int t = i >> 8, c = i & 255;
    v_lds[i] = kvx[((size_t)(b0 * TT + t)) * 512 + 256 + c];
  }
  int h = tid >> 5, lt = tid & 31;
  float kreg[HDD];
  {
    const float* kp = kvx + ((size_t)(b0 * TT + lt)) * 512 + h * HDD;
#pragma unroll
    for (int d = 0; d < HDD; ++d) kreg[d] = kp[d];
  }
  __syncthreads();
  const float scale = 0.17677669529663687f;
  for (int ni = 0; ni < 16; ++ni) {
    int n = n0 + ni;
    int b = batch[n];
    const bf16* qp = qx + (size_t)n * DD + h * HDD;
    float s = 0.f;
    if (b == b0) {
#pragma unroll
      for (int d = 0; d < HDD; ++d) s += (float)qp[d] * kreg[d];
    } else {
      const float* kp = kvx + ((size_t)(b * TT + lt)) * 512 + h * HDD;
#pragma unroll
      for (int d = 0; d < HDD; ++d) s += (float)qp[d] * kp[d];
    }
    s *= scale;
    float mx = s;
#pragma unroll
    for (int o = 16; o > 0; o >>= 1) mx = fmaxf(mx, __shfl_xor(mx, o, 32));
    float e = __expf(s - mx);
    float sum = e;
#pragma unroll
    for (int o = 16; o > 0; o >>= 1) sum += __shfl_xor(sum, o, 32);
    float a = e / sum;
    float o_acc = 0.f;
    int base_lane = (h & 1) << 5;
    if (b == b0) {
#pragma unroll
      for (int t = 0; t < TT; ++t) {
        float at = __shfl(a, base_lane + t, 64);
        o_acc += at * v_lds[t * DD + h * HDD + lt];
      }
    } else {
#pragma unroll
      for (int t = 0; t < TT; ++t) {
        float at = __shfl(a, base_lane + t, 64);
        o_acc += at * kvx[((size_t)(b * TT + t)) * 512 + 256 + h * HDD + lt];
      }
    }
    attnout[(size_t)n * DD + h * HDD + lt] = (bf16)o_acc;
  }
}

// ---------------- host launch ----------------
extern "C" void kernel_launch(void* const* d_in, const int* in_sizes, int n_in,
                              void* d_out, int out_size, void* d_ws, size_t ws_size,
                              hipStream_t stream) {
  const float* x = (const float*)d_in[0];
  const int* ei = (const int*)d_in[1];
  const float* eattr = (const float*)d_in[2];
  const float* v = (const float*)d_in[3];
  const int* batch = (const int*)d_in[4];
  const float* n1_g = (const float*)d_in[5];
  const float* n1_b = (const float*)d_in[6];
  const float* vn_g = (const float*)d_in[7];
  const float* vn_b = (const float*)d_in[8];
  const float* n3_g = (const float*)d_in[9];
  const float* n3_b = (const float*)d_in[10];
  const float* n4_g = (const float*)d_in[11];
  const float* n4_b = (const float*)d_in[12];
  const float* gine_eps = (const float*)d_in[13];
  const float* g_w1 = (const float*)d_in[14];
  const float* g_b1 = (const float*)d_in[15];
  const float* g_lng = (const float*)d_in[16];
  const float* g_lnb = (const float*)d_in[17];
  const float* g_w2 = (const float*)d_in[18];
  const float* g_b2 = (const float*)d_in[19];
  const float* gamma1 = (const float*)d_in[20];
  const float* gamma2 = (const float*)d_in[21];
  const float* gamma3 = (const float*)d_in[22];
  const float* mha_in_w = (const float*)d_in[23];
  const float* mha_in_b = (const float*)d_in[24];
  const float* mha_out_w = (const float*)d_in[25];
  const float* mha_out_b = (const float*)d_in[26];
  const float* q_w = (const float*)d_in[27];
  const float* q_b = (const float*)d_in[28];
  const float* kv_w = (const float*)d_in[29];
  const float* kv_b = (const float*)d_in[30];
  const float* o_w = (const float*)d_in[31];
  const float* o_b = (const float*)d_in[32];
  const float* f_w1 = (const float*)d_in[33];
  const float* f_b1 = (const float*)d_in[34];
  const float* f_w2 = (const float*)d_in[35];
  const float* f_b2 = (const float*)d_in[36];

  float* out_x = (float*)d_out;
  float* out_v = (float*)d_out + (size_t)NN * DD;

  char* wsp = (char*)d_ws;
  size_t off = 0;
  auto alloc = [&](size_t bytes) -> void* {
    void* p = wsp + off;
    off += (bytes + 255) & ~(size_t)255;
    return p;
  };
  // aliased arenas (lifetimes disjoint)
  float* t1f = (float*)alloc(33554432);  // S1: spare
  bf16* xn_bf = (bf16*)alloc(8388608);   // S2: xn -> later qx
  bf16* qx_bf = xn_bf;
  bf16* t1g_bf = (bf16*)alloc(16777216); // S3: t1g bf16 -> later x2 f32
  float* x2f = (float*)t1g_bf;
  float* x1f = (float*)alloc(16777216);  // S4
  bf16* hin_bf = (bf16*)alloc(8388608);  // S5: hin -> later xn3
  bf16* xn3_bf = hin_bf;
  bf16* att_bf = (bf16*)alloc(8388608);  // S6: attnout -> later xn4 (same rows per block)
  bf16* xn4_bf = att_bf;
  // contiguous zero region: deg | summary | cntf
  int* deg = (int*)alloc(NN * 4);
  float* summary = (float*)alloc(BB * DD * 4);
  float* cntf = (float*)alloc(BB * 4);
  int* offs = (int*)alloc((NN + 1) * 4);
  int* woff = (int*)alloc(NN * 4);
  int2* csr2 = (int2*)alloc((size_t)EE * 8);
  bf16* vn_bf = (bf16*)alloc(BB * TT * DD * 2);
  bf16* ctx_bf = (bf16*)alloc(BB * (TT + 1) * DD * 2);
  float* qhf = (float*)alloc(BB * TT * DD * 4);
  float* kvhf = (float*)alloc(BB * (TT + 1) * 512 * 4);
  bf16* vatt_bf = (bf16*)alloc(BB * TT * DD * 2);
  bf16* vout_bf = (bf16*)alloc(BB * TT * DD * 2);
  float* kvxf = (float*)alloc(BB * TT * 512 * 4);
  bf16* wbuf = (bf16*)alloc((size_t)1310720 * 2);
  (void)t1f;

  bf16* g_w1b = wbuf;
  bf16* g_w2b = g_w1b + 131072;
  bf16* mha_in_wb = g_w2b + 131072;
  bf16* q_wb = mha_in_wb + 196608;
  bf16* kv_wb = q_wb + 65536;
  bf16* o_wb = kv_wb + 131072;
  bf16* f_w1b = o_wb + 65536;
  bf16* f_w2b = f_w1b + 262144;
  bf16* mha_out_wb = f_w2b + 262144;

  // 0. zero deg+summary+cntf (contiguous; alloc pads each to 256B)
  hipMemsetAsync(deg, 0, NN * 4 + BB * DD * 4 + 256, stream);

  // 1. fused prologue
  Pro pr;
  pr.wsrc[0] = g_w1; pr.wdst[0] = g_w1b;
  pr.wsrc[1] = g_w2; pr.wdst[1] = g_w2b;
  pr.wsrc[2] = mha_in_w; pr.wdst[2] = mha_in_wb;
  pr.wsrc[3] = mha_out_w; pr.wdst[3] = mha_out_wb;
  pr.wsrc[4] = q_w; pr.wdst[4] = q_wb;
  pr.wsrc[5] = kv_w; pr.wdst[5] = kv_wb;
  pr.wsrc[6] = o_w; pr.wdst[6] = o_wb;
  pr.wsrc[7] = f_w1; pr.wdst[7] = f_w1b;
  pr.wsrc[8] = f_w2; pr.wdst[8] = f_w2b;
  int bs[10] = {0, 128, 256, 448, 512, 576, 704, 768, 1024, 1280};
  for (int i = 0; i < 10; ++i) pr.wblk[i] = bs[i];
  pr.x = x; pr.n1_g = n1_g; pr.n1_b = n1_b; pr.xn = xn_bf;
  pr.v = v; pr.vn_g = vn_g; pr.vn_b = vn_b; pr.vn = vn_bf;
  pr.batch = batch; pr.cntf = cntf;
  pr.ei = ei; pr.deg = deg;
  prologue<<<6528, 256, 0, stream>>>(pr);

  // 2. CSR scan
  scan16k<<<1, 1024, 0, stream>>>(deg, offs, woff);

  // 3. CSR fill + qh gemm (qh: vn @ wq.T, M=256, nbx=4, 8 blocks)
  GemmP j_qh = {vn_bf, mha_in_wb, mha_in_b, BB * TT, 256, 256, GM_F32,
                nullptr, nullptr, qhf, nullptr};
  csr_fill_qh<<<1024 + 8, 256, 0, stream>>>(ei, woff, csr2, j_qh);

  // 4. GINE aggregation (wave per node)
  gine_agg<<<NN / 4, 256, 0, stream>>>(eattr, xn_bf, offs, csr2, gine_eps, hin_bf);

  // 5. g_w1 gemm fused with LN512+gelu -> t1g
  gemm_g1_ln<<<NN / 32, 256, 0, stream>>>(hin_bf, g_w1b, g_b1, g_lng, g_lnb, t1g_bf);

  // 6. g_w2 gemm + residual(x,gamma1) -> x1f, fused LN3 -> xn3, fused seg-sum -> summary
  ResLnP j_g2 = {t1g_bf, g_w2b, g_b2, x, gamma1, x1f, n3_g, n3_b, xn3_bf,
                 512, 1, batch, summary};
  gemm_res_ln<<<NN / 32, 256, 0, stream>>>(j_g2);

  // 7. build ctx + q gemm (xn3 -> qx)
  GemmP j_q = {xn3_bf, q_wb, q_b, NN, 256, 256, GM_BF16, nullptr, nullptr, nullptr, qx_bf};
  mid2<<<BB * (TT + 1) + 512, 256, 0, stream>>>(summary, cntf, vn_bf, ctx_bf, j_q);

  // 8. kvh gemm (M=264 -> nby=3)
  GemmP j_kvh = {ctx_bf, mha_in_wb + (size_t)256 * 256, mha_in_b + 256, BB * (TT + 1), 256, 512,
                 GM_F32, nullptr, nullptr, kvhf, nullptr};
  gemm_one<<<24, 256, 0, stream>>>(j_kvh, 8);

  // 9. small MHA
  mha_small<<<BB, 256, 0, stream>>>(qhf, kvhf, vatt_bf);

  // 10. mha out gemm -> out_v + vout_bf
  GemmP j_mo = {vatt_bf, mha_out_wb, mha_out_b, BB * TT, 256, 256, GM_RES2, v, gamma2, out_v, vout_bf};
  gemm_one<<<8, 256, 0, stream>>>(j_mo, 4);

  // 11. kv gemm -> kvx
  GemmP j_kv = {vout_bf, kv_wb, kv_b, BB * TT, 256, 512, GM_F32, nullptr, nullptr, kvxf, nullptr};
  gemm_one<<<16, 256, 0, stream>>>(j_kv, 8);

  // 12. cross attention
  cross_attn<<<NN / 16, 256, 0, stream>>>(qx_bf, kvxf, batch, att_bf);

  // 13. o gemm + residual(x1f,gamma3) -> x2f, fused LN4 -> xn4
  ResLnP j_o = {att_bf, o_wb, o_b, x1f, gamma3, x2f, n4_g, n4_b, xn4_bf,
                256, 0, nullptr, nullptr};
  gemm_res_ln<<<NN / 32, 256, 0, stream>>>(j_o);

  // 14. fused FFN: out_x = x2f + gelu(xn4 @ f_w1.T + f_b1) @ f_w2.T + f_b2
  gemm_ffn<<<NN / 32, 256, 0, stream>>>(xn4_bf, f_w1b, f_b1, f_w2b, f_b2, x2f, out_x);
}

// Round 4
// 852.165 us; speedup vs baseline: 1.1140x; 1.0429x over previous
//
#include <hip/hip_runtime.h>
#include <math.h>

#define NN 16384
#define EE 262144
#define BB 8
#define TT 32
#define DD 256
#define HH 8
#define HDD 32

typedef __bf16 bf16;
typedef __bf16 bf16x8 __attribute__((ext_vector_type(8)));
typedef __bf16 bf16x4 __attribute__((ext_vector_type(4)));
typedef float f32x4 __attribute__((ext_vector_type(4)));

#define GM_F32 0
#define GM_BF16 1

__device__ __forceinline__ float gelu_f(float v) {
  return 0.5f * v * (1.f + erff(v * 0.70710678118654752440f));
}

// ---------------- LN for one 256-wide row: ONE WAVE per row ----------------
__device__ __forceinline__ void ln256w(const float* __restrict__ xr,
                                       const float* __restrict__ g,
                                       const float* __restrict__ bb,
                                       bf16* __restrict__ o) {
  int lane = threadIdx.x & 63;
  float4 v = *(const float4*)(xr + lane * 4);
  float s = v.x + v.y + v.z + v.w;
  float s2 = v.x * v.x + v.y * v.y + v.z * v.z + v.w * v.w;
#pragma unroll
  for (int off = 32; off > 0; off >>= 1) {
    s += __shfl_xor(s, off, 64);
    s2 += __shfl_xor(s2, off, 64);
  }
  float m = s * (1.f / 256.f);
  float rs = rsqrtf(s2 * (1.f / 256.f) - m * m + 1e-5f);
  float4 gg = *(const float4*)(g + lane * 4);
  float4 bv = *(const float4*)(bb + lane * 4);
  bf16x4 ov;
  ov[0] = (bf16)((v.x - m) * rs * gg.x + bv.x);
  ov[1] = (bf16)((v.y - m) * rs * gg.y + bv.y);
  ov[2] = (bf16)((v.z - m) * rs * gg.z + bv.z);
  ov[3] = (bf16)((v.w - m) * rs * gg.w + bv.w);
  *(bf16x4*)(o + lane * 4) = ov;
}

// ---------------- fused prologue: cast9 | LN(x) | LN(v) | cnt | deg ----------------
struct Pro {
  const float* wsrc[9];
  bf16* wdst[9];
  int wblk[10];
  const float* x; const float* n1_g; const float* n1_b; bf16* xn;
  const float* v; const float* vn_g; const float* vn_b; bf16* vn;
  const int* batch; float* cntf;
  const int* ei; int* deg;
};

__global__ __launch_bounds__(256) void prologue(Pro p) {
  __shared__ int hist[BB];
  int b = blockIdx.x, t = threadIdx.x;
  int wave = t >> 6;
  if (b < 1280) {
    int s = 0;
    while (b >= p.wblk[s + 1]) ++s;
    int i = (b - p.wblk[s]) * 1024 + t * 4;
    const float4 f = *(const float4*)(p.wsrc[s] + i);
    bf16x4 o;
    o[0] = (bf16)f.x; o[1] = (bf16)f.y; o[2] = (bf16)f.z; o[3] = (bf16)f.w;
    *(bf16x4*)(p.wdst[s] + i) = o;
  } else if (b < 5376) {
    size_t r = (size_t)(b - 1280) * 4 + wave;
    ln256w(p.x + r * 256, p.n1_g, p.n1_b, p.xn + r * 256);
  } else if (b < 5440) {
    size_t r = (size_t)(b - 5376) * 4 + wave;
    ln256w(p.v + r * 256, p.vn_g, p.vn_b, p.vn + r * 256);
  } else if (b < 5504) {
    if (t < BB) hist[t] = 0;
    __syncthreads();
    int n = (b - 5440) * 256 + t;
    atomicAdd(&hist[p.batch[n]], 1);
    __syncthreads();
    if (t < BB) {
      int h = hist[t];
      if (h) atomicAdd(&p.cntf[t], (float)h);
    }
  } else {
    int e = (b - 5504) * 256 + t;
    atomicAdd(&p.deg[p.ei[EE + e]], 1);
  }
}

// ---------------- CSR build ----------------
__global__ __launch_bounds__(1024) void scan16k(const int* __restrict__ deg,
                                                int* __restrict__ offs, int* __restrict__ woff) {
  __shared__ int part[1024];
  int t = threadIdx.x;
  int base = t * 16;
  int v[16];
  int s = 0;
#pragma unroll
  for (int j = 0; j < 16; ++j) { v[j] = deg[base + j]; s += v[j]; }
  part[t] = s;
  __syncthreads();
  for (int o = 1; o < 1024; o <<= 1) {
    int x = (t >= o) ? part[t - o] : 0;
    __syncthreads();
    part[t] += x;
    __syncthreads();
  }
  int excl = part[t] - s;
#pragma unroll
  for (int j = 0; j < 16; ++j) {
    offs[base + j] = excl;
    woff[base + j] = excl;
    excl += v[j];
  }
  if (t == 1023) offs[NN] = part[1023];
}

// ---------------- MFMA GEMM core (32 rows x 64 cols per wave, 128x64+ per block) ----------------
struct GemmP {
  const bf16* A; const bf16* W; const float* bias;
  int M, K, NC, mode;
  float* outf; bf16* outb;
};

__device__ __forceinline__ void gemm_core(const GemmP p, int bx, int by) {
  int wave = threadIdx.x >> 6;
  int lane = threadIdx.x & 63;
  int qd = lane >> 4;
  int l16 = lane & 15;
  int r0 = by * 128 + wave * 32;
  int c0 = bx * 64;
  int ar0 = r0 + l16;       if (ar0 >= p.M) ar0 = p.M - 1;
  int ar1 = r0 + 16 + l16;  if (ar1 >= p.M) ar1 = p.M - 1;
  const bf16* Ap0 = p.A + (size_t)ar0 * p.K + qd * 8;
  const bf16* Ap1 = p.A + (size_t)ar1 * p.K + qd * 8;
  const bf16* Wp = p.W + (size_t)(c0 + l16) * p.K + qd * 8;
  size_t K16 = (size_t)16 * p.K;
  f32x4 acc00 = {0.f, 0.f, 0.f, 0.f};
  f32x4 acc01 = acc00, acc02 = acc00, acc03 = acc00;
  f32x4 acc10 = acc00, acc11 = acc00, acc12 = acc00, acc13 = acc00;
  bf16x8 a0, a1, b0, b1, b2, b3, na0, na1, nb0, nb1, nb2, nb3;

#define GLOADS(A0, A1, B0, B1, B2, B3, kk)                \
  A0 = *(const bf16x8*)(Ap0 + (kk));                      \
  A1 = *(const bf16x8*)(Ap1 + (kk));                      \
  B0 = *(const bf16x8*)(Wp + (kk));                       \
  B1 = *(const bf16x8*)(Wp + K16 + (kk));                 \
  B2 = *(const bf16x8*)(Wp + 2 * K16 + (kk));             \
  B3 = *(const bf16x8*)(Wp + 3 * K16 + (kk));
#define GMFMAS(A0, A1, B0, B1, B2, B3)                                  \
  acc00 = __builtin_amdgcn_mfma_f32_16x16x32_bf16(A0, B0, acc00, 0, 0, 0); \
  acc01 = __builtin_amdgcn_mfma_f32_16x16x32_bf16(A0, B1, acc01, 0, 0, 0); \
  acc02 = __builtin_amdgcn_mfma_f32_16x16x32_bf16(A0, B2, acc02, 0, 0, 0); \
  acc03 = __builtin_amdgcn_mfma_f32_16x16x32_bf16(A0, B3, acc03, 0, 0, 0); \
  acc10 = __builtin_amdgcn_mfma_f32_16x16x32_bf16(A1, B0, acc10, 0, 0, 0); \
  acc11 = __builtin_amdgcn_mfma_f32_16x16x32_bf16(A1, B1, acc11, 0, 0, 0); \
  acc12 = __builtin_amdgcn_mfma_f32_16x16x32_bf16(A1, B2, acc12, 0, 0, 0); \
  acc13 = __builtin_amdgcn_mfma_f32_16x16x32_bf16(A1, B3, acc13, 0, 0, 0);

  GLOADS(a0, a1, b0, b1, b2, b3, 0)
  int k = 32;
  for (; k + 32 < p.K; k += 64) {
    GLOADS(na0, na1, nb0, nb1, nb2, nb3, k)
    GMFMAS(a0, a1, b0, b1, b2, b3)
    GLOADS(a0, a1, b0, b1, b2, b3, k + 32)
    GMFMAS(na0, na1, nb0, nb1, nb2, nb3)
  }
  GLOADS(na0, na1, nb0, nb1, nb2, nb3, k)
  GMFMAS(a0, a1, b0, b1, b2, b3)
  GMFMAS(na0, na1, nb0, nb1, nb2, nb3)
#undef GLOADS
#undef GMFMAS

  f32x4 accs[2][4] = {{acc00, acc01, acc02, acc03}, {acc10, acc11, acc12, acc13}};
#pragma unroll
  for (int s = 0; s < 2; ++s) {
#pragma unroll
    for (int c = 0; c < 4; ++c) {
      int col = c0 + c * 16 + l16;
      float bv = p.bias[col];
#pragma unroll
      for (int i = 0; i < 4; ++i) {
        int row = r0 + s * 16 + qd * 4 + i;
        if (row >= p.M) continue;
        size_t idx = (size_t)row * p.NC + col;
        float v = accs[s][c][i] + bv;
        if (p.mode == GM_F32) p.outf[idx] = v;
        else p.outb[idx] = (bf16)v;
      }
    }
  }
}

// csr_fill + qh gemm merged (blocks [0,8) qh, [8,1032) fill)
__global__ __launch_bounds__(256) void csr_fill_qh(const int* __restrict__ ei,
                                                   int* __restrict__ woff,
                                                   int2* __restrict__ csr2, GemmP qp) {
  int b = blockIdx.x;
  if (b < 8) {
    gemm_core(qp, b % 4, b / 4);
  } else {
    int e = (b - 8) * 256 + threadIdx.x;
    int d = ei[EE + e];
    int s = ei[e];
    int p = atomicAdd(&woff[d], 1);
    csr2[p] = make_int2(e, s);
  }
}

// GINE aggregation: ONE WAVE per node (4 nodes/block)
__global__ __launch_bounds__(256) void gine_agg(const float* __restrict__ eattr,
                                                const bf16* __restrict__ xn,
                                                const int* __restrict__ offs,
                                                const int2* __restrict__ csr2,
                                                const float* __restrict__ epsp,
                                                bf16* __restrict__ hin) {
  int wave = threadIdx.x >> 6, lane = threadIdx.x & 63;
  int n = blockIdx.x * 4 + wave;
  int s0 = offs[n], s1 = offs[n + 1];
  f32x4 acc = {0.f, 0.f, 0.f, 0.f};
  int i = s0;
  int2 es = (i < s1) ? csr2[i] : make_int2(0, 0);
  for (; i < s1; ++i) {
    int2 cur = es;
    if (i + 1 < s1) es = csr2[i + 1];
    float4 ea = *(const float4*)(eattr + (size_t)cur.x * DD + lane * 4);
    bf16x4 xv = *(const bf16x4*)(xn + (size_t)cur.y * DD + lane * 4);
    acc[0] += fmaxf((float)xv[0] + ea.x, 0.f);
    acc[1] += fmaxf((float)xv[1] + ea.y, 0.f);
    acc[2] += fmaxf((float)xv[2] + ea.z, 0.f);
    acc[3] += fmaxf((float)xv[3] + ea.w, 0.f);
  }
  bf16x4 xs = *(const bf16x4*)(xn + (size_t)n * DD + lane * 4);
  float e1 = 1.f + epsp[0];
  bf16x4 o;
#pragma unroll
  for (int j = 0; j < 4; ++j)
    o[j] = (bf16)(e1 * (float)xs[j] + acc[j]);
  *(bf16x4*)(hin + (size_t)n * DD + lane * 4) = o;
}

// ---------------- fused G-branch MLP: g1+LN512+gelu (LDS) then g2+res+LN3+segsum ----------------
// block = 32 rows.
struct G12P {
  const bf16* A; const bf16* W1; const float* b1;
  const float* lng; const float* lnb;
  const bf16* W2; const float* b2;
  const float* res; const float* gamma;
  float* resout; const float* n3g; const float* n3b; bf16* xn3;
  const int* batch; float* summary;
};

__global__ __launch_bounds__(256) void gemm_g1g2(G12P p) {
  __shared__ bf16 t_l[32 * 520];  // 33 KB; stride 520 bf16 = 1040B = 4 dwords mod 32 banks
  __shared__ float ssum[4][32], ssum2[4][32], smm[32], smr[32];
  int w = threadIdx.x >> 6, lane = threadIdx.x & 63;
  int qd = lane >> 4, l16 = lane & 15;
  int r0 = blockIdx.x * 32;
  // ---- phase 1: t = gelu(LN512(A @ W1.T + b1)) -> LDS
  {
    int c0 = w * 128;
    const bf16* Ap0 = p.A + (size_t)(r0 + l16) * 256 + qd * 8;
    const bf16* Ap1 = Ap0 + (size_t)16 * 256;
    const bf16* Wp = p.W1 + (size_t)(c0 + l16) * 256 + qd * 8;
    f32x4 z = {0.f, 0.f, 0.f, 0.f};
    f32x4 acc0[8], acc1[8];
#pragma unroll
    for (int cf = 0; cf < 8; ++cf) { acc0[cf] = z; acc1[cf] = z; }
    for (int k = 0; k < 256; k += 32) {
      bf16x8 a0 = *(const bf16x8*)(Ap0 + k);
      bf16x8 a1 = *(const bf16x8*)(Ap1 + k);
#pragma unroll
      for (int cf = 0; cf < 8; ++cf) {
        bf16x8 bv = *(const bf16x8*)(Wp + (size_t)cf * 16 * 256 + k);
        acc0[cf] = __builtin_amdgcn_mfma_f32_16x16x32_bf16(a0, bv, acc0[cf], 0, 0, 0);
        acc1[cf] = __builtin_amdgcn_mfma_f32_16x16x32_bf16(a1, bv, acc1[cf], 0, 0, 0);
      }
    }
#pragma unroll
    for (int cf = 0; cf < 8; ++cf) {
      float bv = p.b1[c0 + cf * 16 + l16];
#pragma unroll
      for (int i = 0; i < 4; ++i) { acc0[cf][i] += bv; acc1[cf][i] += bv; }
    }
#pragma unroll
    for (int s = 0; s < 2; ++s) {
#pragma unroll
      for (int i = 0; i < 4; ++i) {
        float ps = 0.f, ps2 = 0.f;
#pragma unroll
        for (int cf = 0; cf < 8; ++cf) {
          float v = s ? acc1[cf][i] : acc0[cf][i];
          ps += v; ps2 += v * v;
        }
#pragma unroll
        for (int off = 8; off > 0; off >>= 1) {
          ps += __shfl_down(ps, off, 16);
          ps2 += __shfl_down(ps2, off, 16);
        }
        if (l16 == 0) { int rib = s * 16 + qd * 4 + i; ssum[w][rib] = ps; ssum2[w][rib] = ps2; }
      }
    }
    __syncthreads();
    if (threadIdx.x < 32) {
      int rib = threadIdx.x;
      float S = ssum[0][rib] + ssum[1][rib] + ssum[2][rib] + ssum[3][rib];
      float S2 = ssum2[0][rib] + ssum2[1][rib] + ssum2[2][rib] + ssum2[3][rib];
      float m = S * (1.f / 512.f);
      smm[rib] = m;
      smr[rib] = rsqrtf(S2 * (1.f / 512.f) - m * m + 1e-5f);
    }
    __syncthreads();
#pragma unroll
    for (int s = 0; s < 2; ++s) {
#pragma unroll
      for (int cf = 0; cf < 8; ++cf) {
        int col = c0 + cf * 16 + l16;
        float g = p.lng[col], b = p.lnb[col];
#pragma unroll
        for (int i = 0; i < 4; ++i) {
          int rib = s * 16 + qd * 4 + i;
          float v = ((s ? acc1[cf][i] : acc0[cf][i]) - smm[rib]) * smr[rib] * g + b;
          t_l[rib * 520 + col] = (bf16)gelu_f(v);
        }
      }
    }
  }
  __syncthreads();
  // ---- phase 2: x1 = res + gamma*(t @ W2.T + b2); LN3 -> xn3; segsum -> summary
  {
    int c0 = w * 64;
    const bf16* lp0 = t_l + l16 * 520 + qd * 8;
    const bf16* lp1 = t_l + (16 + l16) * 520 + qd * 8;
    const bf16* Wp = p.W2 + (size_t)(c0 + l16) * 512 + qd * 8;
    f32x4 z = {0.f, 0.f, 0.f, 0.f};
    f32x4 acc0[4], acc1[4];
#pragma unroll
    for (int cf = 0; cf < 4; ++cf) { acc0[cf] = z; acc1[cf] = z; }
    for (int k = 0; k < 512; k += 32) {
      bf16x8 a0 = *(const bf16x8*)(lp0 + k);
      bf16x8 a1 = *(const bf16x8*)(lp1 + k);
#pragma unroll
      for (int cf = 0; cf < 4; ++cf) {
        bf16x8 bv = *(const bf16x8*)(Wp + (size_t)cf * 16 * 512 + k);
        acc0[cf] = __builtin_amdgcn_mfma_f32_16x16x32_bf16(a0, bv, acc0[cf], 0, 0, 0);
        acc1[cf] = __builtin_amdgcn_mfma_f32_16x16x32_bf16(a1, bv, acc1[cf], 0, 0, 0);
      }
    }
    float rr0[4][4], rr1[4][4];
#pragma unroll
    for (int cf = 0; cf < 4; ++cf) {
      int col = c0 + cf * 16 + l16;
      float bv = p.b2[col], gm = p.gamma[col];
#pragma unroll
      for (int i = 0; i < 4; ++i) {
        {
          int row = r0 + qd * 4 + i;
          size_t idx = (size_t)row * 256 + col;
          float r = p.res[idx] + gm * (acc0[cf][i] + bv);
          p.resout[idx] = r; rr0[cf][i] = r;
        }
        {
          int row = r0 + 16 + qd * 4 + i;
          size_t idx = (size_t)row * 256 + col;
          float r = p.res[idx] + gm * (acc1[cf][i] + bv);
          p.resout[idx] = r; rr1[cf][i] = r;
        }
      }
    }
    __syncthreads();  // protect ssum reuse
#pragma unroll
    for (int s = 0; s < 2; ++s) {
#pragma unroll
      for (int i = 0; i < 4; ++i) {
        float ps = 0.f, ps2 = 0.f;
#pragma unroll
        for (int cf = 0; cf < 4; ++cf) {
          float v = s ? rr1[cf][i] : rr0[cf][i];
          ps += v; ps2 += v * v;
        }
#pragma unroll
        for (int off = 8; off > 0; off >>= 1) {
          ps += __shfl_down(ps, off, 16);
          ps2 += __shfl_down(ps2, off, 16);
        }
        if (l16 == 0) { int rib = s * 16 + qd * 4 + i; ssum[w][rib] = ps; ssum2[w][rib] = ps2; }
      }
    }
    __syncthreads();
    if (threadIdx.x < 32) {
      int rib = threadIdx.x;
      float S = ssum[0][rib] + ssum[1][rib] + ssum[2][rib] + ssum[3][rib];
      float S2 = ssum2[0][rib] + ssum2[1][rib] + ssum2[2][rib] + ssum2[3][rib];
      float m = S * (1.f / 256.f);
      smm[rib] = m;
      smr[rib] = rsqrtf(S2 * (1.f / 256.f) - m * m + 1e-5f);
    }
    __syncthreads();
#pragma unroll
    for (int cf = 0; cf < 4; ++cf) {
      int col = c0 + cf * 16 + l16;
      float lg = p.n3g[col], lb = p.n3b[col];
#pragma unroll
      for (int i = 0; i < 4; ++i) {
        {
          int rib = qd * 4 + i;
          p.xn3[(size_t)(r0 + rib) * 256 + col] =
              (bf16)((rr0[cf][i] - smm[rib]) * smr[rib] * lg + lb);
        }
        {
          int rib = 16 + qd * 4 + i;
          p.xn3[(size_t)(r0 + rib) * 256 + col] =
              (bf16)((rr1[cf][i] - smm[rib]) * smr[rib] * lg + lb);
        }
      }
    }
    // segment-sum into summary
    int b0 = p.batch[r0], b31 = p.batch[r0 + 31];
    if (b0 == b31) {
#pragma unroll
      for (int cf = 0; cf < 4; ++cf) {
        float sl = 0.f;
#pragma unroll
        for (int i = 0; i < 4; ++i) sl += rr0[cf][i] + rr1[cf][i];
        sl += __shfl_xor(sl, 16, 64);
        sl += __shfl_xor(sl, 32, 64);
        if (qd == 0) atomicAdd(&p.summary[(size_t)b0 * 256 + c0 + cf * 16 + l16], sl);
      }
    } else {
#pragma unroll
      for (int cf = 0; cf < 4; ++cf) {
        int col = c0 + cf * 16 + l16;
#pragma unroll
        for (int i = 0; i < 4; ++i) {
          atomicAdd(&p.summary[(size_t)p.batch[r0 + qd * 4 + i] * 256 + col], rr0[cf][i]);
          atomicAdd(&p.summary[(size_t)p.batch[r0 + 16 + qd * 4 + i] * 256 + col], rr1[cf][i]);
        }
      }
    }
  }
}

// ---------------- GEMM + residual + LN(256) (o-branch) ----------------
struct ResLnP {
  const bf16* A; const bf16* W; const float* bias;
  const float* res; const float* gamma;
  float* resout; const float* lng; const float* lnb; bf16* lnout;
  int K;
};

__global__ __launch_bounds__(256) void gemm_res_ln(ResLnP p) {
  __shared__ float ssum[4][32], ssum2[4][32], smm[32], smr[32];
  int w = threadIdx.x >> 6, lane = threadIdx.x & 63;
  int qd = lane >> 4, l16 = lane & 15;
  int r0 = blockIdx.x * 32;
  int c0 = w * 64;
  const bf16* Ap0 = p.A + (size_t)(r0 + l16) * p.K + qd * 8;
  const bf16* Ap1 = Ap0 + (size_t)16 * p.K;
  const bf16* Wp = p.W + (size_t)(c0 + l16) * p.K + qd * 8;
  size_t K16 = (size_t)16 * p.K;
  f32x4 z = {0.f, 0.f, 0.f, 0.f};
  f32x4 acc0[4], acc1[4];
#pragma unroll
  for (int cf = 0; cf < 4; ++cf) { acc0[cf] = z; acc1[cf] = z; }
  for (int k = 0; k < p.K; k += 32) {
    bf16x8 a0 = *(const bf16x8*)(Ap0 + k);
    bf16x8 a1 = *(const bf16x8*)(Ap1 + k);
#pragma unroll
    for (int cf = 0; cf < 4; ++cf) {
      bf16x8 bv = *(const bf16x8*)(Wp + cf * K16 + k);
      acc0[cf] = __builtin_amdgcn_mfma_f32_16x16x32_bf16(a0, bv, acc0[cf], 0, 0, 0);
      acc1[cf] = __builtin_amdgcn_mfma_f32_16x16x32_bf16(a1, bv, acc1[cf], 0, 0, 0);
    }
  }
  float rr0[4][4], rr1[4][4];
#pragma unroll
  for (int cf = 0; cf < 4; ++cf) {
    int col = c0 + cf * 16 + l16;
    float bv = p.bias[col], gm = p.gamma[col];
#pragma unroll
    for (int i = 0; i < 4; ++i) {
      {
        int row = r0 + qd * 4 + i;
        size_t idx = (size_t)row * 256 + col;
        float r = p.res[idx] + gm * (acc0[cf][i] + bv);
        p.resout[idx] = r; rr0[cf][i] = r;
      }
      {
        int row = r0 + 16 + qd * 4 + i;
        size_t idx = (size_t)row * 256 + col;
        float r = p.res[idx] + gm * (acc1[cf][i] + bv);
        p.resout[idx] = r; rr1[cf][i] = r;
      }
    }
  }
#pragma unroll
  for (int s = 0; s < 2; ++s) {
#pragma unroll
    for (int i = 0; i < 4; ++i) {
      float ps = 0.f, ps2 = 0.f;
#pragma unroll
      for (int cf = 0; cf < 4; ++cf) {
        float v = s ? rr1[cf][i] : rr0[cf][i];
        ps += v; ps2 += v * v;
      }
#pragma unroll
      for (int off = 8; off > 0; off >>= 1) {
        ps += __shfl_down(ps, off, 16);
        ps2 += __shfl_down(ps2, off, 16);
      }
      if (l16 == 0) { int rib = s * 16 + qd * 4 + i; ssum[w][rib] = ps; ssum2[w][rib] = ps2; }
    }
  }
  __syncthreads();
  if (threadIdx.x < 32) {
    int rib = threadIdx.x;
    float S = ssum[0][rib] + ssum[1][rib] + ssum[2][rib] + ssum[3][rib];
    float S2 = ssum2[0][rib] + ssum2[1][rib] + ssum2[2][rib] + ssum2[3][rib];
    float m = S * (1.f / 256.f);
    smm[rib] = m;
    smr[rib] = rsqrtf(S2 * (1.f / 256.f) - m * m + 1e-5f);
  }
  __syncthreads();
#pragma unroll
  for (int cf = 0; cf < 4; ++cf) {
    int col = c0 + cf * 16 + l16;
    float lg = p.lng[col], lb = p.lnb[col];
#pragma unroll
    for (int i = 0; i < 4; ++i) {
      {
        int rib = qd * 4 + i;
        p.lnout[(size_t)(r0 + rib) * 256 + col] =
            (bf16)((rr0[cf][i] - smm[rib]) * smr[rib] * lg + lb);
      }
      {
        int rib = 16 + qd * 4 + i;
        p.lnout[(size_t)(r0 + rib) * 256 + col] =
            (bf16)((rr1[cf][i] - smm[rib]) * smr[rib] * lg + lb);
      }
    }
  }
}

// ---------------- fused FFN ----------------
__global__ __launch_bounds__(256) void gemm_ffn(const bf16* __restrict__ A,
                                                const bf16* __restrict__ W1,
                                                const float* __restrict__ b1,
                                                const bf16* __restrict__ W2,
                                                const float* __restrict__ b2,
                                                const float* __restrict__ res,
                                                float* __restrict__ outx) {
  __shared__ bf16 t_lds[32 * 1032];
  int w = threadIdx.x >> 6, lane = threadIdx.x & 63;
  int qd = lane >> 4, l16 = lane & 15;
  int r0 = blockIdx.x * 32;
  {
    int c0 = w * 256;
    const bf16* Ap0 = A + (size_t)(r0 + l16) * 256 + qd * 8;
    const bf16* Ap1 = Ap0 + (size_t)16 * 256;
    const bf16* Wp = W1 + (size_t)(c0 + l16) * 256 + qd * 8;
    f32x4 z = {0.f, 0.f, 0.f, 0.f};
    f32x4 acc0[16], acc1[16];
#pragma unroll
    for (int cf = 0; cf < 16; ++cf) { acc0[cf] = z; acc1[cf] = z; }
    for (int k = 0; k < 256; k += 32) {
      bf16x8 a0 = *(const bf16x8*)(Ap0 + k);
      bf16x8 a1 = *(const bf16x8*)(Ap1 + k);
#pragma unroll
      for (int cf = 0; cf < 16; ++cf) {
        bf16x8 bv = *(const bf16x8*)(Wp + (size_t)cf * 16 * 256 + k);
        acc0[cf] = __builtin_amdgcn_mfma_f32_16x16x32_bf16(a0, bv, acc0[cf], 0, 0, 0);
        acc1[cf] = __builtin_amdgcn_mfma_f32_16x16x32_bf16(a1, bv, acc1[cf], 0, 0, 0);
      }
    }
#pragma unroll
    for (int cf = 0; cf < 16; ++cf) {
      int col = c0 + cf * 16 + l16;
      float bv = b1[col];
#pragma unroll
      for (int i = 0; i < 4; ++i) {
        int rib0 = qd * 4 + i, rib1 = 16 + qd * 4 + i;
        t_lds[rib0 * 1032 + col] = (bf16)gelu_f(acc0[cf][i] + bv);
        t_lds[rib1 * 1032 + col] = (bf16)gelu_f(acc1[cf][i] + bv);
      }
    }
  }
  __syncthreads();
  {
    int c2 = w * 64;
    const bf16* Wp2 = W2 + (size_t)(c2 + l16) * 1024 + qd * 8;
    const bf16* lp0 = t_lds + l16 * 1032 + qd * 8;
    const bf16* lp1 = t_lds + (16 + l16) * 1032 + qd * 8;
    f32x4 z = {0.f, 0.f, 0.f, 0.f};
    f32x4 acc0[4], acc1[4];
#pragma unroll
    for (int cf = 0; cf < 4; ++cf) { acc0[cf] = z; acc1[cf] = z; }
    for (int k = 0; k < 1024; k += 32) {
      bf16x8 a0 = *(const bf16x8*)(lp0 + k);
      bf16x8 a1 = *(const bf16x8*)(lp1 + k);
#pragma unroll
      for (int cf = 0; cf < 4; ++cf) {
        bf16x8 bv = *(const bf16x8*)(Wp2 + (size_t)cf * 16 * 1024 + k);
        acc0[cf] = __builtin_amdgcn_mfma_f32_16x16x32_bf16(a0, bv, acc0[cf], 0, 0, 0);
        acc1[cf] = __builtin_amdgcn_mfma_f32_16x16x32_bf16(a1, bv, acc1[cf], 0, 0, 0);
      }
    }
#pragma unroll
    for (int cf = 0; cf < 4; ++cf) {
      int col = c2 + cf * 16 + l16;
      float bv = b2[col];
#pragma unroll
      for (int i = 0; i < 4; ++i) {
        int row0 = r0 + qd * 4 + i, row1 = row0 + 16;
        size_t i0 = (size_t)row0 * 256 + col, i1 = (size_t)row1 * 256 + col;
        outx[i0] = res[i0] + acc0[cf][i] + bv;
        outx[i1] = res[i1] + acc1[cf][i] + bv;
      }
    }
  }
}

// ---------------- q-gemm + fused v-branch tail ----------------
// blocks [0,8): per-batch tail (ctx->kvh->mha->mo->kv, all LDS-staged)
// blocks [8,520): q gemm
struct VtP {
  const bf16* vn; const float* summary; const float* cntf; const float* qh;
  const bf16* wkv_in; const float* bkv_in;   // mha_in rows 256..767, bias+256
  const bf16* wmo; const float* bmo;
  const float* vres; const float* gamma2; float* outv;
  const bf16* wkv2; const float* bkv2; float* kvx;
};

__global__ __launch_bounds__(256) void q_vtail(GemmP qp, VtP vt) {
  // LDS overlay: [0, 8768): ctx(33x264) then vatt(32x264); [8768, 25928): kvh(33x520) then vout(32x264)
  __shared__ bf16 sl[25928];
  int blk = blockIdx.x;
  if (blk >= 8) {
    int l = blk - 8;
    gemm_core(qp, l % 4, l / 4);
    return;
  }
  int bb = blk;
  int t = threadIdx.x;
  int w = t >> 6, lane = t & 63, qd = lane >> 4, l16 = lane & 15;
  bf16* ctx_l = sl;           // 33 x 264
  bf16* kvh_l = sl + 8768;    // 33 x 520  (cols 0-255 K, 256-511 V)
  bf16* vatt_l = sl;          // 32 x 264
  bf16* vout_l = sl + 8768;   // 32 x 264
  const float scale = 0.17677669529663687f;

  // phase 0: build ctx rows (32 vn rows + summary row)
  {
    float cinv = 1.f / fmaxf(vt.cntf[bb], 1.f);
    for (int r = 0; r < 33; ++r) {
      float val;
      if (r < 32) val = (float)vt.vn[((size_t)(bb * 32 + r)) * 256 + t];
      else val = vt.summary[(size_t)bb * 256 + t] * cinv;
      ctx_l[r * 264 + t] = (bf16)val;
    }
  }
  __syncthreads();

  // phase 1: kvh[33][512] = ctx @ wkv_in.T + bkv_in  (48-row padded, rows>=33 discarded)
  {
    const bf16* a0p = ctx_l + (l16 < 32 ? l16 : 32) * 264 + qd * 8;
    const bf16* a1p = ctx_l + ((16 + l16) < 32 ? (16 + l16) : 32) * 264 + qd * 8;
    const bf16* a2p = ctx_l + 32 * 264 + qd * 8;
#pragma unroll
    for (int sc = 0; sc < 2; ++sc) {
      int c0 = w * 128 + sc * 64;
      const bf16* Wp = vt.wkv_in + (size_t)(c0 + l16) * 256 + qd * 8;
      f32x4 z = {0.f, 0.f, 0.f, 0.f};
      f32x4 acc[3][4];
#pragma unroll
      for (int rg = 0; rg < 3; ++rg)
#pragma unroll
        for (int cf = 0; cf < 4; ++cf) acc[rg][cf] = z;
      for (int k = 0; k < 256; k += 32) {
        bf16x8 av0 = *(const bf16x8*)(a0p + k);
        bf16x8 av1 = *(const bf16x8*)(a1p + k);
        bf16x8 av2 = *(const bf16x8*)(a2p + k);
#pragma unroll
        for (int cf = 0; cf < 4; ++cf) {
          bf16x8 bv = *(const bf16x8*)(Wp + (size_t)cf * 16 * 256 + k);
          acc[0][cf] = __builtin_amdgcn_mfma_f32_16x16x32_bf16(av0, bv, acc[0][cf], 0, 0, 0);
          acc[1][cf] = __builtin_amdgcn_mfma_f32_16x16x32_bf16(av1, bv, acc[1][cf], 0, 0, 0);
          acc[2][cf] = __builtin_amdgcn_mfma_f32_16x16x32_bf16(av2, bv, acc[2][cf], 0, 0, 0);
        }
      }
#pragma unroll
      for (int cf = 0; cf < 4; ++cf) {
        int col = c0 + cf * 16 + l16;
        float bv = vt.bkv_in[col];
#pragma unroll
        for (int rg = 0; rg < 3; ++rg) {
#pragma unroll
          for (int i = 0; i < 4; ++i) {
            int row = rg * 16 + qd * 4 + i;
            if (row < 33) kvh_l[row * 520 + col] = (bf16)(acc[rg][cf][i] + bv);
          }
        }
      }
    }
  }
  __syncthreads();

  // phase 2: mha -> vatt (overwrites ctx region)
  {
    int h = t >> 5, qi = t & 31;
    float qreg[HDD];
    const float* qp = vt.qh + ((size_t)(bb * TT + qi)) * DD + h * HDD;
#pragma unroll
    for (int d = 0; d < HDD; ++d) qreg[d] = qp[d];
    float sc[TT + 1];
    float mx = -1e30f;
#pragma unroll
    for (int k = 0; k < TT + 1; ++k) {
      float s = 0.f;
#pragma unroll
      for (int d = 0; d < HDD; ++d) s += qreg[d] * (float)kvh_l[k * 520 + h * HDD + d];
      s *= scale;
      sc[k] = s;
      mx = fmaxf(mx, s);
    }
    float sum = 0.f;
#pragma unroll
    for (int k = 0; k < TT + 1; ++k) {
      sc[k] = __expf(sc[k] - mx);
      sum += sc[k];
    }
    float inv = 1.f / sum;
#pragma unroll
    for (int d = 0; d < HDD; ++d) {
      float o = 0.f;
#pragma unroll
      for (int k = 0; k < TT + 1; ++k)
        o += sc[k] * (float)kvh_l[k * 520 + 256 + h * HDD + d];
      vatt_l[qi * 264 + h * HDD + d] = (bf16)(o * inv);
    }
  }
  __syncthreads();

  // phase 3: mo gemm: v_upd = vatt @ wmo.T + bmo; r = vres + gamma2*v_upd -> outv + vout_l
  {
    int c0 = w * 64;
    const bf16* a0p = vatt_l + l16 * 264 + qd * 8;
    const bf16* a1p = vatt_l + (16 + l16) * 264 + qd * 8;
    const bf16* Wp = vt.wmo + (size_t)(c0 + l16) * 256 + qd * 8;
    f32x4 z = {0.f, 0.f, 0.f, 0.f};
    f32x4 acc0[4], acc1[4];
#pragma unroll
    for (int cf = 0; cf < 4; ++cf) { acc0[cf] = z; acc1[cf] = z; }
    for (int k = 0; k < 256; k += 32) {
      bf16x8 a0 = *(const bf16x8*)(a0p + k);
      bf16x8 a1 = *(const bf16x8*)(a1p + k);
#pragma unroll
      for (int cf = 0; cf < 4; ++cf) {
        bf16x8 bv = *(const bf16x8*)(Wp + (size_t)cf * 16 * 256 + k);
        acc0[cf] = __builtin_amdgcn_mfma_f32_16x16x32_bf16(a0, bv, acc0[cf], 0, 0, 0);
        acc1[cf] = __builtin_amdgcn_mfma_f32_16x16x32_bf16(a1, bv, acc1[cf], 0, 0, 0);
      }
    }
#pragma unroll
    for (int cf = 0; cf < 4; ++cf) {
      int col = c0 + cf * 16 + l16;
      float bv = vt.bmo[col], gm = vt.gamma2[col];
#pragma unroll
      for (int i = 0; i < 4; ++i) {
        {
          int row = qd * 4 + i;
          size_t idx = (size_t)(bb * TT + row) * 256 + col;
          float r = vt.vres[idx] + gm * (acc0[cf][i] + bv);
          vt.outv[idx] = r;
          vout_l[row * 264 + col] = (bf16)r;
        }
        {
          int row = 16 + qd * 4 + i;
          size_t idx = (size_t)(bb * TT + row) * 256 + col;
          float r = vt.vres[idx] + gm * (acc1[cf][i] + bv);
          vt.outv[idx] = r;
          vout_l[row * 264 + col] = (bf16)r;
        }
      }
    }
  }
  __syncthreads();

  // phase 4: kv gemm: kvx[32][512] = vout @ wkv2.T + bkv2 (f32 global)
  {
    const bf16* a0p = vout_l + l16 * 264 + qd * 8;
    const bf16* a1p = vout_l + (16 + l16) * 264 + qd * 8;
#pragma unroll
    for (int sc = 0; sc < 2; ++sc) {
      int c0 = w * 128 + sc * 64;
      const bf16* Wp = vt.wkv2 + (size_t)(c0 + l16) * 256 + qd * 8;
      f32x4 z = {0.f, 0.f, 0.f, 0.f};
      f32x4 acc0[4], acc1[4];
#pragma unroll
      for (int cf = 0; cf < 4; ++cf) { acc0[cf] = z; acc1[cf] = z; }
      for (int k = 0; k < 256; k += 32) {
        bf16x8 a0 = *(const bf16x8*)(a0p + k);
        bf16x8 a1 = *(const bf16x8*)(a1p + k);
#pragma unroll
        for (int cf = 0; cf < 4; ++cf) {
          bf16x8 bv = *(const bf16x8*)(Wp + (size_t)cf * 16 * 256 + k);
          acc0[cf] = __builtin_amdgcn_mfma_f32_16x16x32_bf16(a0, bv, acc0[cf], 0, 0, 0);
          acc1[cf] = __builtin_amdgcn_mfma_f32_16x16x32_bf16(a1, bv, acc1[cf], 0, 0, 0);
        }
      }
#pragma unroll
      for (int cf = 0; cf < 4; ++cf) {
        int col = c0 + cf * 16 + l16;
        float bv = vt.bkv2[col];
#pragma unroll
        for (int i = 0; i < 4; ++i) {
          {
            int row = qd * 4 + i;
            vt.kvx[(size_t)(bb * TT + row) * 512 + col] = acc0[cf][i] + bv;
          }
          {
            int row = 16 + qd * 4 + i;
            vt.kvx[(size_t)(bb * TT + row) * 512 + col] = acc1[cf][i] + bv;
          }
        }
      }
    }
  }
}

// ---------------- per-node cross attention (16 nodes per block) ----------------
__global__ __launch_bounds__(256) void cross_attn(const bf16* __restrict__ qx,
                                                  const float* __restrict__ kvx,
                                                  const int* __restrict__ batch,
                                                  bf16* __restrict__ attnout) {
  __shared__ float v_lds[TT * DD];  // 32 KB
  int tid = threadIdx.x;
  int n0 = blockIdx.x * 16;
  int b0 = batch[n0];
  for (int i = tid; i < TT * DD; i += 256) {
    int t = i >> 8, c = i & 255;
    v_lds[i] = kvx[((size_t)(b0 * TT + t)) * 512 + 256 + c];
  }
  int h = tid >> 5, lt = tid & 31;
  float kreg[HDD];
  {
    const float* kp = kvx + ((size_t)(b0 * TT + lt)) * 512 + h * HDD;
#pragma unroll
    for (int d = 0; d < HDD; ++d) kreg[d] = kp[d];
  }
  __syncthreads();
  const float scale = 0.17677669529663687f;
  for (int ni = 0; ni < 16; ++ni) {
    int n = n0 + ni;
    int b = batch[n];
    const bf16* qp = qx + (size_t)n * DD + h * HDD;
    float s = 0.f;
    if (b == b0) {
#pragma unroll
      for (int d = 0; d < HDD; ++d) s += (float)qp[d] * kreg[d];
    } else {
      const float* kp = kvx + ((size_t)(b * TT + lt)) * 512 + h * HDD;
#pragma unroll
      for (int d = 0; d < HDD; ++d) s += (float)qp[d] * kp[d];
    }
    s *= scale;
    float mx = s;
#pragma unroll
    for (int o = 16; o > 0; o >>= 1) mx = fmaxf(mx, __shfl_xor(mx, o, 32));
    float e = __expf(s - mx);
    float sum = e;
#pragma unroll
    for (int o = 16; o > 0; o >>= 1) sum += __shfl_xor(sum, o, 32);
    float a = e / sum;
    float o_acc = 0.f;
    int base_lane = (h & 1) << 5;
    if (b == b0) {
#pragma unroll
      for (int t = 0; t < TT; ++t) {
        float at = __shfl(a, base_lane + t, 64);
        o_acc += at * v_lds[t * DD + h * HDD + lt];
      }
    } else {
#pragma unroll
      for (int t = 0; t < TT; ++t) {
        float at = __shfl(a, base_lane + t, 64);
        o_acc += at * kvx[((size_t)(b * TT + t)) * 512 + 256 + h * HDD + lt];
      }
    }
    attnout[(size_t)n * DD + h * HDD + lt] = (bf16)o_acc;
  }
}

// ---------------- host launch ----------------
extern "C" void kernel_launch(void* const* d_in, const int* in_sizes, int n_in,
                              void* d_out, int out_size, void* d_ws, size_t ws_size,
                              hipStream_t stream) {
  const float* x = (const float*)d_in[0];
  const int* ei = (const int*)d_in[1];
  const float* eattr = (const float*)d_in[2];
  const float* v = (const float*)d_in[3];
  const int* batch = (const int*)d_in[4];
  const float* n1_g = (const float*)d_in[5];
  const float* n1_b = (const float*)d_in[6];
  const float* vn_g = (const float*)d_in[7];
  const float* vn_b = (const float*)d_in[8];
  const float* n3_g = (const float*)d_in[9];
  const float* n3_b = (const float*)d_in[10];
  const float* n4_g = (const float*)d_in[11];
  const float* n4_b = (const float*)d_in[12];
  const float* gine_eps = (const float*)d_in[13];
  const float* g_w1 = (const float*)d_in[14];
  const float* g_b1 = (const float*)d_in[15];
  const float* g_lng = (const float*)d_in[16];
  const float* g_lnb = (const float*)d_in[17];
  const float* g_w2 = (const float*)d_in[18];
  const float* g_b2 = (const float*)d_in[19];
  const float* gamma1 = (const float*)d_in[20];
  const float* gamma2 = (const float*)d_in[21];
  const float* gamma3 = (const float*)d_in[22];
  const float* mha_in_w = (const float*)d_in[23];
  const float* mha_in_b = (const float*)d_in[24];
  const float* mha_out_w = (const float*)d_in[25];
  const float* mha_out_b = (const float*)d_in[26];
  const float* q_w = (const float*)d_in[27];
  const float* q_b = (const float*)d_in[28];
  const float* kv_w = (const float*)d_in[29];
  const float* kv_b = (const float*)d_in[30];
  const float* o_w = (const float*)d_in[31];
  const float* o_b = (const float*)d_in[32];
  const float* f_w1 = (const float*)d_in[33];
  const float* f_b1 = (const float*)d_in[34];
  const float* f_w2 = (const float*)d_in[35];
  const float* f_b2 = (const float*)d_in[36];

  float* out_x = (float*)d_out;
  float* out_v = (float*)d_out + (size_t)NN * DD;

  char* wsp = (char*)d_ws;
  size_t off = 0;
  auto alloc = [&](size_t bytes) -> void* {
    void* p = wsp + off;
    off += (bytes + 255) & ~(size_t)255;
    return p;
  };
  float* t1f = (float*)alloc(33554432);  // spare
  bf16* xn_bf = (bf16*)alloc(8388608);   // xn -> later qx
  bf16* qx_bf = xn_bf;
  bf16* t1g_bf = (bf16*)alloc(16777216); // -> x2 f32
  float* x2f = (float*)t1g_bf;
  float* x1f = (float*)alloc(16777216);
  bf16* hin_bf = (bf16*)alloc(8388608);  // hin -> later xn3
  bf16* xn3_bf = hin_bf;
  bf16* att_bf = (bf16*)alloc(8388608);  // attnout -> later xn4 (same rows per block)
  bf16* xn4_bf = att_bf;
  // contiguous zero region: deg | summary | cntf
  int* deg = (int*)alloc(NN * 4);
  float* summary = (float*)alloc(BB * DD * 4);
  float* cntf = (float*)alloc(BB * 4);
  int* offs = (int*)alloc((NN + 1) * 4);
  int* woff = (int*)alloc(NN * 4);
  int2* csr2 = (int2*)alloc((size_t)EE * 8);
  bf16* vn_bf = (bf16*)alloc(BB * TT * DD * 2);
  float* qhf = (float*)alloc(BB * TT * DD * 4);
  float* kvxf = (float*)alloc(BB * TT * 512 * 4);
  bf16* wbuf = (bf16*)alloc((size_t)1310720 * 2);
  (void)t1f;

  bf16* g_w1b = wbuf;
  bf16* g_w2b = g_w1b + 131072;
  bf16* mha_in_wb = g_w2b + 131072;
  bf16* q_wb = mha_in_wb + 196608;
  bf16* kv_wb = q_wb + 65536;
  bf16* o_wb = kv_wb + 131072;
  bf16* f_w1b = o_wb + 65536;
  bf16* f_w2b = f_w1b + 262144;
  bf16* mha_out_wb = f_w2b + 262144;

  // 0. zero deg+summary+cntf
  hipMemsetAsync(deg, 0, NN * 4 + BB * DD * 4 + 256, stream);

  // 1. fused prologue
  Pro pr;
  pr.wsrc[0] = g_w1; pr.wdst[0] = g_w1b;
  pr.wsrc[1] = g_w2; pr.wdst[1] = g_w2b;
  pr.wsrc[2] = mha_in_w; pr.wdst[2] = mha_in_wb;
  pr.wsrc[3] = mha_out_w; pr.wdst[3] = mha_out_wb;
  pr.wsrc[4] = q_w; pr.wdst[4] = q_wb;
  pr.wsrc[5] = kv_w; pr.wdst[5] = kv_wb;
  pr.wsrc[6] = o_w; pr.wdst[6] = o_wb;
  pr.wsrc[7] = f_w1; pr.wdst[7] = f_w1b;
  pr.wsrc[8] = f_w2; pr.wdst[8] = f_w2b;
  int bs[10] = {0, 128, 256, 448, 512, 576, 704, 768, 1024, 1280};
  for (int i = 0; i < 10; ++i) pr.wblk[i] = bs[i];
  pr.x = x; pr.n1_g = n1_g; pr.n1_b = n1_b; pr.xn = xn_bf;
  pr.v = v; pr.vn_g = vn_g; pr.vn_b = vn_b; pr.vn = vn_bf;
  pr.batch = batch; pr.cntf = cntf;
  pr.ei = ei; pr.deg = deg;
  prologue<<<6528, 256, 0, stream>>>(pr);

  // 2. CSR scan
  scan16k<<<1, 1024, 0, stream>>>(deg, offs, woff);

  // 3. qh gemm (blocks 0-7) + CSR fill
  GemmP j_qh = {vn_bf, mha_in_wb, mha_in_b, BB * TT, 256, 256, GM_F32, qhf, nullptr};
  csr_fill_qh<<<1024 + 8, 256, 0, stream>>>(ei, woff, csr2, j_qh);

  // 4. GINE aggregation (wave per node)
  gine_agg<<<NN / 4, 256, 0, stream>>>(eattr, xn_bf, offs, csr2, gine_eps, hin_bf);

  // 5. fused g1(+LN512+gelu) + g2(+res+LN3+segsum)
  G12P jg = {hin_bf, g_w1b, g_b1, g_lng, g_lnb, g_w2b, g_b2, x, gamma1,
             x1f, n3_g, n3_b, xn3_bf, batch, summary};
  gemm_g1g2<<<NN / 32, 256, 0, stream>>>(jg);

  // 6. v-tail (blocks 0-7) + q gemm (blocks 8-519)
  GemmP j_q = {xn3_bf, q_wb, q_b, NN, 256, 256, GM_BF16, nullptr, qx_bf};
  VtP vt;
  vt.vn = vn_bf; vt.summary = summary; vt.cntf = cntf; vt.qh = qhf;
  vt.wkv_in = mha_in_wb + (size_t)256 * 256; vt.bkv_in = mha_in_b + 256;
  vt.wmo = mha_out_wb; vt.bmo = mha_out_b;
  vt.vres = v; vt.gamma2 = gamma2; vt.outv = out_v;
  vt.wkv2 = kv_wb; vt.bkv2 = kv_b; vt.kvx = kvxf;
  q_vtail<<<8 + 512, 256, 0, stream>>>(j_q, vt);

  // 7. cross attention
  cross_attn<<<NN / 16, 256, 0, stream>>>(qx_bf, kvxf, batch, att_bf);

  // 8. o gemm + residual(x1f,gamma3) -> x2f, fused LN4 -> xn4
  ResLnP j_o = {att_bf, o_wb, o_b, x1f, gamma3, x2f, n4_g, n4_b, xn4_bf, 256};
  gemm_res_ln<<<NN / 32, 256, 0, stream>>>(j_o);

  // 9. fused FFN: out_x = x2f + gelu(xn4 @ f_w1.T + f_b1) @ f_w2.T + f_b2
  gemm_ffn<<<NN / 32, 256, 0, stream>>>(xn4_bf, f_w1b, f_b1, f_w2b, f_b2, x2f, out_x);
}